// Round 9
// baseline (311.585 us; speedup 1.0000x reference)
//
#include <hip/hip_runtime.h>
#include <hip/hip_bf16.h>

// GraphSparseConvolution on MI355X.
// Round 9: line-exclusive rec chunks. tile_hist pads each (tile,bucket)
// count to PAD records (PAD in {8,4,2,1} chosen to fit ws). multisplit
// fills pad slots with no-op records {bin_local=tile&255, col=0, val=0};
// they flow through bucket_sort/spmm as exact no-ops. Kills the cross-XCD
// false-sharing RMW that kept multisplit at ~80us. TILE 2048 -> 4096.
// Rest unchanged from round 8. Fallback to atomic path if ws too small.

static constexpr int O_DIM = 128;
static constexpr float KEEP_INV = 1.0f / 0.9f;  // 1/keep_prob
static constexpr int BUCK_BINS = 256;           // rows per coarse bucket
static constexpr int TILE = 4096;               // edges per multisplit tile

using half_t = _Float16;
using half2_t = _Float16 __attribute__((ext_vector_type(2)));

// ---------------------------------------------------------------------------
// Detect how the harness materialized the bool keep_mask (int32/f32/uint8).
__global__ void detect_mask_kernel(const unsigned int* __restrict__ w, int nwords,
                                   int* __restrict__ flags) {
    __shared__ int sA[256];
    __shared__ int sB[256];
    int t = threadIdx.x;
    int violA = 0, violB = 0;
    for (int i = t; i < nwords; i += 256) {
        unsigned int x = w[i];
        violA |= (x > 1u) ? 1 : 0;
        violB |= (x != 0u && x != 0x3F800000u) ? 1 : 0;
    }
    sA[t] = violA; sB[t] = violB;
    __syncthreads();
    for (int s = 128; s > 0; s >>= 1) {
        if (t < s) { sA[t] |= sA[t + s]; sB[t] |= sB[t + s]; }
        __syncthreads();
    }
    if (t == 0) { flags[0] = sA[0]; flags[1] = sB[0]; }
}

// ---------------------------------------------------------------------------
// kernel matrix f32 -> f16 (once; 16384 half2).
__global__ void conv_kern_kernel(const float2* __restrict__ kern2,
                                 half2_t* __restrict__ k16, int n) {
    int i = blockIdx.x * 256 + threadIdx.x;
    if (i < n) {
        float2 v = kern2[i];
        half2_t o; o.x = (half_t)v.x; o.y = (half_t)v.y;
        k16[i] = o;
    }
}

// ---------------------------------------------------------------------------
// A) per-tile bucket histogram, PADDED to `pad` records per chunk, written
// transposed: histT[k*B + b].
__global__ __launch_bounds__(256) void tile_hist_kernel(
        const int* __restrict__ xr, int nnz_x,
        const int* __restrict__ ar, int nnz_a,
        int n_nodes, int nbuck, int B, int pad,
        int* __restrict__ histT) {
    __shared__ int hist[1024];
    int b = blockIdx.x, t = threadIdx.x;
    for (int k = t; k < 1024; k += 256) hist[k] = 0;
    __syncthreads();
    int tot = nnz_x + nnz_a;
    int tstart = b * TILE;
    int tend = min(tstart + TILE, tot);
    for (int i = tstart + t; i < tend; i += 256) {
        int bin = (i < nnz_x) ? xr[i] : (n_nodes + ar[i - nnz_x]);
        atomicAdd(&hist[bin >> 8], 1);
    }
    __syncthreads();
    int pm = pad - 1;
    for (int k = t; k < nbuck; k += 256)
        histT[(size_t)k * B + b] = (hist[k] + pm) & ~pm;
}

// ---------------------------------------------------------------------------
// 3-phase exclusive scan over cnt[0..n) -> S[0..n).
static constexpr int SCAN_BS = 256;
static constexpr int SCAN_IPT = 8;
static constexpr int SCAN_CHUNK = SCAN_BS * SCAN_IPT;  // 2048

__global__ __launch_bounds__(SCAN_BS) void scan_partial_kernel(const int* __restrict__ cnt,
                                                               int n, int* __restrict__ bsums) {
    int b = blockIdx.x, t = threadIdx.x;
    int lane = t & 63, wid = t >> 6;
    __shared__ int wsum[SCAN_BS / 64];
    int base = b * SCAN_CHUNK + t * SCAN_IPT;
    int s = 0;
    #pragma unroll
    for (int k = 0; k < SCAN_IPT; ++k) {
        int i = base + k;
        s += (i < n) ? cnt[i] : 0;
    }
    #pragma unroll
    for (int d = 1; d < 64; d <<= 1) s += __shfl_xor(s, d, 64);
    if (lane == 0) wsum[wid] = s;
    __syncthreads();
    if (t == 0) {
        int tot = 0;
        #pragma unroll
        for (int w = 0; w < SCAN_BS / 64; ++w) tot += wsum[w];
        bsums[b] = tot;
    }
}

__global__ __launch_bounds__(1024) void scan_blocksums_kernel(int* __restrict__ bsums, int nb,
                                                              int* __restrict__ sent0,
                                                              int* __restrict__ sent1) {
    __shared__ int wsum[16];
    int t = threadIdx.x, lane = t & 63, wid = t >> 6;
    int v = (t < nb) ? bsums[t] : 0;
    int s = v;
    #pragma unroll
    for (int d = 1; d < 64; d <<= 1) {
        int u = __shfl_up(s, d, 64);
        if (lane >= d) s += u;
    }
    if (lane == 63) wsum[wid] = s;
    __syncthreads();
    int woff = 0;
    for (int w = 0; w < wid; ++w) woff += wsum[w];
    if (t < nb) bsums[t] = woff + s - v;      // exclusive
    if (t == 1023) { int tot = woff + s; *sent0 = tot; *sent1 = tot; }
}

__global__ __launch_bounds__(SCAN_BS) void scan_final_kernel(const int* __restrict__ cnt, int n,
                                                             const int* __restrict__ bsums,
                                                             int* __restrict__ S) {
    __shared__ int wsum[SCAN_BS / 64];
    int b = blockIdx.x, t = threadIdx.x;
    int lane = t & 63, wid = t >> 6;
    int base = b * SCAN_CHUNK + t * SCAN_IPT;
    int v[SCAN_IPT];
    int tsum = 0;
    #pragma unroll
    for (int k = 0; k < SCAN_IPT; ++k) {
        int i = base + k;
        v[k] = (i < n) ? cnt[i] : 0;
        tsum += v[k];
    }
    int s = tsum;
    #pragma unroll
    for (int d = 1; d < 64; d <<= 1) {
        int u = __shfl_up(s, d, 64);
        if (lane >= d) s += u;
    }
    if (lane == 63) wsum[wid] = s;
    __syncthreads();
    int woff = 0;
    for (int w = 0; w < wid; ++w) woff += wsum[w];
    int excl = bsums[b] + woff + (s - tsum);
    #pragma unroll
    for (int k = 0; k < SCAN_IPT; ++k) {
        int i = base + k;
        if (i < n) S[i] = excl;
        excl += v[k];
    }
}

// ---------------------------------------------------------------------------
// C) multisplit: deterministic placement via LDS cursors seeded from tofs,
// then pad-fill each chunk's tail with no-op records (line-exclusive writes).
__global__ __launch_bounds__(256) void multisplit_kernel(
        const float* __restrict__ xv,
        const int* __restrict__ xr,
        const int* __restrict__ xc,
        const void* __restrict__ mask,
        const int* __restrict__ flags,
        const float* __restrict__ av,
        const int* __restrict__ ar,
        const int* __restrict__ ac,
        int nnz_x, int nnz_a, int n_nodes,
        int nbuck, int B,
        const int* __restrict__ tofs,
        int2* __restrict__ rec) {
    __shared__ int cur[1024];
    int b = blockIdx.x, t = threadIdx.x;
    for (int k = t; k < nbuck; k += 256)
        cur[k] = tofs[(size_t)k * B + b];
    __syncthreads();
    int tot = nnz_x + nnz_a;
    int tstart = b * TILE;
    int tend = min(tstart + TILE, tot);
    int f0 = flags[0], f1 = flags[1];
    for (int i = tstart + t; i < tend; i += 256) {
        int bin, col; float v;
        if (i < nnz_x) {
            bin = xr[i];
            col = xc[i];
            bool keep;
            if (f0 == 0)      keep = ((const int*)mask)[i] != 0;
            else if (f1 == 0) keep = ((const float*)mask)[i] != 0.0f;
            else              keep = ((const unsigned char*)mask)[i] != 0;
            v = keep ? xv[i] * KEEP_INV : 0.0f;
        } else {
            int e = i - nnz_x;
            bin = n_nodes + ar[e];
            col = ac[e];
            v = av[e];
        }
        int key = ((bin & (BUCK_BINS - 1)) << 17) | col;
        int pos = atomicAdd(&cur[bin >> 8], 1);   // LDS atomic — cheap
        rec[pos] = make_int2(key, __float_as_int(v));
    }
    __syncthreads();
    // pad-fill: no-op records, spread across rows via bin_local = tile&255
    int fillkey = (b & (BUCK_BINS - 1)) << 17;    // col 0, val 0
    for (int k = t; k < nbuck; k += 256) {
        int fl = k * B + b;
        int pe = tofs[fl + 1];
        for (int p = cur[k]; p < pe; ++p)
            rec[p] = make_int2(fillkey, 0);
    }
}

// ---------------------------------------------------------------------------
// D) per-bucket LDS counting sort -> packed records + row_start S.
// (pads sort like normal records; they are exact no-ops downstream)
__global__ __launch_bounds__(256) void bucket_sort_kernel(
        const int2* __restrict__ rec,
        const int* __restrict__ tofs, int B,
        int ntot, int2* __restrict__ packed,
        int* __restrict__ S) {
    __shared__ int hist[256];
    __shared__ int cur[256];
    __shared__ int wsum[4];
    int bb = blockIdx.x, t = threadIdx.x;
    int start = tofs[(size_t)bb * B];
    int end   = tofs[(size_t)(bb + 1) * B];
    hist[t] = 0;
    __syncthreads();
    for (int i = start + t; i < end; i += 256) {
        unsigned k = (unsigned)rec[i].x;
        atomicAdd(&hist[k >> 17], 1);
    }
    __syncthreads();
    int v = hist[t];
    int lane = t & 63, wid = t >> 6;
    int s = v;
    #pragma unroll
    for (int d = 1; d < 64; d <<= 1) {
        int u = __shfl_up(s, d, 64);
        if (lane >= d) s += u;
    }
    if (lane == 63) wsum[wid] = s;
    __syncthreads();
    int woff = 0;
    for (int w = 0; w < wid; ++w) woff += wsum[w];
    int excl = woff + s - v;
    int binBase = bb << 8;
    if (binBase + t < ntot) S[binBase + t] = start + excl;
    cur[t] = start + excl;
    __syncthreads();
    for (int i = start + t; i < end; i += 256) {
        int2 e = rec[i];
        unsigned k = (unsigned)e.x;
        int pos = atomicAdd(&cur[k >> 17], 1);
        packed[pos] = make_int2((int)(k & 0x1FFFFu), e.y);
    }
}

// ---------------------------------------------------------------------------
// E) SpMM1: wave-per-row, f16 weight gathers, int4 edge loads, 8-deep
// pipeline with 4-deep + scalar tails. src = k16 (half2), dst = h (f16x2).
__global__ __launch_bounds__(256) void spmm1_wave_kernel(
        const int* __restrict__ S, const int2* __restrict__ packed,
        const half2_t* __restrict__ k16, half2_t* __restrict__ h2,
        int n_rows) {
    int gid = blockIdx.x * 256 + threadIdx.x;
    int r = gid >> 6;
    if (r >= n_rows) return;
    int lane = gid & 63;
    int j = S[r], end = S[r + 1];
    float ax = 0.0f, ay = 0.0f;
    if ((j & 1) && j < end) {   // peel to 16B-align packed reads
        int2 e = packed[j];
        half2_t w = k16[e.x * 64 + lane];
        float v = __int_as_float(e.y);
        ax = fmaf(v, (float)w.x, ax); ay = fmaf(v, (float)w.y, ay);
        ++j;
    }
    for (; j + 8 <= end; j += 8) {
        int4 p0 = *(const int4*)(packed + j);
        int4 p1 = *(const int4*)(packed + j + 2);
        int4 p2 = *(const int4*)(packed + j + 4);
        int4 p3 = *(const int4*)(packed + j + 6);
        half2_t w0 = k16[p0.x * 64 + lane];
        half2_t w1 = k16[p0.z * 64 + lane];
        half2_t w2 = k16[p1.x * 64 + lane];
        half2_t w3 = k16[p1.z * 64 + lane];
        half2_t w4 = k16[p2.x * 64 + lane];
        half2_t w5 = k16[p2.z * 64 + lane];
        half2_t w6 = k16[p3.x * 64 + lane];
        half2_t w7 = k16[p3.z * 64 + lane];
        float v0 = __int_as_float(p0.y), v1 = __int_as_float(p0.w);
        float v2 = __int_as_float(p1.y), v3 = __int_as_float(p1.w);
        float v4 = __int_as_float(p2.y), v5 = __int_as_float(p2.w);
        float v6 = __int_as_float(p3.y), v7 = __int_as_float(p3.w);
        ax = fmaf(v0, (float)w0.x, ax); ay = fmaf(v0, (float)w0.y, ay);
        ax = fmaf(v1, (float)w1.x, ax); ay = fmaf(v1, (float)w1.y, ay);
        ax = fmaf(v2, (float)w2.x, ax); ay = fmaf(v2, (float)w2.y, ay);
        ax = fmaf(v3, (float)w3.x, ax); ay = fmaf(v3, (float)w3.y, ay);
        ax = fmaf(v4, (float)w4.x, ax); ay = fmaf(v4, (float)w4.y, ay);
        ax = fmaf(v5, (float)w5.x, ax); ay = fmaf(v5, (float)w5.y, ay);
        ax = fmaf(v6, (float)w6.x, ax); ay = fmaf(v6, (float)w6.y, ay);
        ax = fmaf(v7, (float)w7.x, ax); ay = fmaf(v7, (float)w7.y, ay);
    }
    if (j + 4 <= end) {
        int4 p0 = *(const int4*)(packed + j);
        int4 p1 = *(const int4*)(packed + j + 2);
        half2_t w0 = k16[p0.x * 64 + lane];
        half2_t w1 = k16[p0.z * 64 + lane];
        half2_t w2 = k16[p1.x * 64 + lane];
        half2_t w3 = k16[p1.z * 64 + lane];
        float v0 = __int_as_float(p0.y), v1 = __int_as_float(p0.w);
        float v2 = __int_as_float(p1.y), v3 = __int_as_float(p1.w);
        ax = fmaf(v0, (float)w0.x, ax); ay = fmaf(v0, (float)w0.y, ay);
        ax = fmaf(v1, (float)w1.x, ax); ay = fmaf(v1, (float)w1.y, ay);
        ax = fmaf(v2, (float)w2.x, ax); ay = fmaf(v2, (float)w2.y, ay);
        ax = fmaf(v3, (float)w3.x, ax); ay = fmaf(v3, (float)w3.y, ay);
        j += 4;
    }
    for (; j < end; ++j) {
        int2 e = packed[j];
        half2_t w = k16[e.x * 64 + lane];
        float v = __int_as_float(e.y);
        ax = fmaf(v, (float)w.x, ax); ay = fmaf(v, (float)w.y, ay);
    }
    half2_t o; o.x = (half_t)ax; o.y = (half_t)ay;
    h2[r * 64 + lane] = o;
}

// ---------------------------------------------------------------------------
// F) SpMM2 + ReLU: wave-per-row, 16-deep gather pipeline with 8/4/scalar
// tails, int4 edge loads.
__global__ __launch_bounds__(256) void spmm2_wave_kernel(
        const int* __restrict__ S, const int2* __restrict__ packed,
        const half2_t* __restrict__ h2, float2* __restrict__ out2,
        int n_rows) {
    int gid = blockIdx.x * 256 + threadIdx.x;
    int r = gid >> 6;
    if (r >= n_rows) return;
    int lane = gid & 63;
    int j = S[r], end = S[r + 1];
    float ax = 0.0f, ay = 0.0f;
    if ((j & 1) && j < end) {
        int2 e = packed[j];
        half2_t w = h2[e.x * 64 + lane];
        float v = __int_as_float(e.y);
        ax = fmaf(v, (float)w.x, ax); ay = fmaf(v, (float)w.y, ay);
        ++j;
    }
    for (; j + 16 <= end; j += 16) {
        int4 p0 = *(const int4*)(packed + j);
        int4 p1 = *(const int4*)(packed + j + 2);
        int4 p2 = *(const int4*)(packed + j + 4);
        int4 p3 = *(const int4*)(packed + j + 6);
        int4 p4 = *(const int4*)(packed + j + 8);
        int4 p5 = *(const int4*)(packed + j + 10);
        int4 p6 = *(const int4*)(packed + j + 12);
        int4 p7 = *(const int4*)(packed + j + 14);
        half2_t w0 = h2[p0.x * 64 + lane];
        half2_t w1 = h2[p0.z * 64 + lane];
        half2_t w2 = h2[p1.x * 64 + lane];
        half2_t w3 = h2[p1.z * 64 + lane];
        half2_t w4 = h2[p2.x * 64 + lane];
        half2_t w5 = h2[p2.z * 64 + lane];
        half2_t w6 = h2[p3.x * 64 + lane];
        half2_t w7 = h2[p3.z * 64 + lane];
        half2_t w8 = h2[p4.x * 64 + lane];
        half2_t w9 = h2[p4.z * 64 + lane];
        half2_t wa = h2[p5.x * 64 + lane];
        half2_t wb = h2[p5.z * 64 + lane];
        half2_t wc = h2[p6.x * 64 + lane];
        half2_t wd = h2[p6.z * 64 + lane];
        half2_t we = h2[p7.x * 64 + lane];
        half2_t wf = h2[p7.z * 64 + lane];
        float v0 = __int_as_float(p0.y), v1 = __int_as_float(p0.w);
        float v2 = __int_as_float(p1.y), v3 = __int_as_float(p1.w);
        float v4 = __int_as_float(p2.y), v5 = __int_as_float(p2.w);
        float v6 = __int_as_float(p3.y), v7 = __int_as_float(p3.w);
        float v8 = __int_as_float(p4.y), v9 = __int_as_float(p4.w);
        float va = __int_as_float(p5.y), vb = __int_as_float(p5.w);
        float vc = __int_as_float(p6.y), vd = __int_as_float(p6.w);
        float ve = __int_as_float(p7.y), vf = __int_as_float(p7.w);
        ax = fmaf(v0, (float)w0.x, ax); ay = fmaf(v0, (float)w0.y, ay);
        ax = fmaf(v1, (float)w1.x, ax); ay = fmaf(v1, (float)w1.y, ay);
        ax = fmaf(v2, (float)w2.x, ax); ay = fmaf(v2, (float)w2.y, ay);
        ax = fmaf(v3, (float)w3.x, ax); ay = fmaf(v3, (float)w3.y, ay);
        ax = fmaf(v4, (float)w4.x, ax); ay = fmaf(v4, (float)w4.y, ay);
        ax = fmaf(v5, (float)w5.x, ax); ay = fmaf(v5, (float)w5.y, ay);
        ax = fmaf(v6, (float)w6.x, ax); ay = fmaf(v6, (float)w6.y, ay);
        ax = fmaf(v7, (float)w7.x, ax); ay = fmaf(v7, (float)w7.y, ay);
        ax = fmaf(v8, (float)w8.x, ax); ay = fmaf(v8, (float)w8.y, ay);
        ax = fmaf(v9, (float)w9.x, ax); ay = fmaf(v9, (float)w9.y, ay);
        ax = fmaf(va, (float)wa.x, ax); ay = fmaf(va, (float)wa.y, ay);
        ax = fmaf(vb, (float)wb.x, ax); ay = fmaf(vb, (float)wb.y, ay);
        ax = fmaf(vc, (float)wc.x, ax); ay = fmaf(vc, (float)wc.y, ay);
        ax = fmaf(vd, (float)wd.x, ax); ay = fmaf(vd, (float)wd.y, ay);
        ax = fmaf(ve, (float)we.x, ax); ay = fmaf(ve, (float)we.y, ay);
        ax = fmaf(vf, (float)wf.x, ax); ay = fmaf(vf, (float)wf.y, ay);
    }
    if (j + 8 <= end) {
        int4 p0 = *(const int4*)(packed + j);
        int4 p1 = *(const int4*)(packed + j + 2);
        int4 p2 = *(const int4*)(packed + j + 4);
        int4 p3 = *(const int4*)(packed + j + 6);
        half2_t w0 = h2[p0.x * 64 + lane];
        half2_t w1 = h2[p0.z * 64 + lane];
        half2_t w2 = h2[p1.x * 64 + lane];
        half2_t w3 = h2[p1.z * 64 + lane];
        half2_t w4 = h2[p2.x * 64 + lane];
        half2_t w5 = h2[p2.z * 64 + lane];
        half2_t w6 = h2[p3.x * 64 + lane];
        half2_t w7 = h2[p3.z * 64 + lane];
        float v0 = __int_as_float(p0.y), v1 = __int_as_float(p0.w);
        float v2 = __int_as_float(p1.y), v3 = __int_as_float(p1.w);
        float v4 = __int_as_float(p2.y), v5 = __int_as_float(p2.w);
        float v6 = __int_as_float(p3.y), v7 = __int_as_float(p3.w);
        ax = fmaf(v0, (float)w0.x, ax); ay = fmaf(v0, (float)w0.y, ay);
        ax = fmaf(v1, (float)w1.x, ax); ay = fmaf(v1, (float)w1.y, ay);
        ax = fmaf(v2, (float)w2.x, ax); ay = fmaf(v2, (float)w2.y, ay);
        ax = fmaf(v3, (float)w3.x, ax); ay = fmaf(v3, (float)w3.y, ay);
        ax = fmaf(v4, (float)w4.x, ax); ay = fmaf(v4, (float)w4.y, ay);
        ax = fmaf(v5, (float)w5.x, ax); ay = fmaf(v5, (float)w5.y, ay);
        ax = fmaf(v6, (float)w6.x, ax); ay = fmaf(v6, (float)w6.y, ay);
        ax = fmaf(v7, (float)w7.x, ax); ay = fmaf(v7, (float)w7.y, ay);
        j += 8;
    }
    if (j + 4 <= end) {
        int4 p0 = *(const int4*)(packed + j);
        int4 p1 = *(const int4*)(packed + j + 2);
        half2_t w0 = h2[p0.x * 64 + lane];
        half2_t w1 = h2[p0.z * 64 + lane];
        half2_t w2 = h2[p1.x * 64 + lane];
        half2_t w3 = h2[p1.z * 64 + lane];
        float v0 = __int_as_float(p0.y), v1 = __int_as_float(p0.w);
        float v2 = __int_as_float(p1.y), v3 = __int_as_float(p1.w);
        ax = fmaf(v0, (float)w0.x, ax); ay = fmaf(v0, (float)w0.y, ay);
        ax = fmaf(v1, (float)w1.x, ax); ay = fmaf(v1, (float)w1.y, ay);
        ax = fmaf(v2, (float)w2.x, ax); ay = fmaf(v2, (float)w2.y, ay);
        ax = fmaf(v3, (float)w3.x, ax); ay = fmaf(v3, (float)w3.y, ay);
        j += 4;
    }
    for (; j < end; ++j) {
        int2 e = packed[j];
        half2_t w = h2[e.x * 64 + lane];
        float v = __int_as_float(e.y);
        ax = fmaf(v, (float)w.x, ax); ay = fmaf(v, (float)w.y, ay);
    }
    out2[r * 64 + lane] = make_float2(fmaxf(ax, 0.0f), fmaxf(ay, 0.0f));
}

// ---------------------------------------------------------------------------
// Fallback atomic path (only if ws too small).
__global__ void spmm1_atomic_kernel(const float* __restrict__ xv,
                                    const int* __restrict__ xr,
                                    const int* __restrict__ xc,
                                    const void* __restrict__ mask,
                                    const float* __restrict__ kern,
                                    const int* __restrict__ flags,
                                    float* __restrict__ h, int nnz) {
    long long gid = (long long)blockIdx.x * blockDim.x + threadIdx.x;
    int e = (int)(gid >> 7);
    if (e >= nnz) return;
    int o = (int)(gid & 127);
    bool keep;
    if (flags[0] == 0)      keep = ((const int*)mask)[e] != 0;
    else if (flags[1] == 0) keep = ((const float*)mask)[e] != 0.0f;
    else                    keep = ((const unsigned char*)mask)[e] != 0;
    if (!keep) return;
    atomicAdd(&h[(long long)xr[e] * O_DIM + o], xv[e] * KEEP_INV * kern[xc[e] * O_DIM + o]);
}

__global__ void spmm2_atomic_kernel(const float* __restrict__ av,
                                    const int* __restrict__ ar,
                                    const int* __restrict__ ac,
                                    const float* __restrict__ h,
                                    float* __restrict__ out, int nnz) {
    long long gid = (long long)blockIdx.x * blockDim.x + threadIdx.x;
    int e = (int)(gid >> 7);
    if (e >= nnz) return;
    int o = (int)(gid & 127);
    atomicAdd(&out[(long long)ar[e] * O_DIM + o], av[e] * h[(long long)ac[e] * O_DIM + o]);
}

__global__ void relu_kernel(float* __restrict__ out, int n4) {
    int stride = gridDim.x * blockDim.x;
    float4* p = (float4*)out;
    for (int i = blockIdx.x * blockDim.x + threadIdx.x; i < n4; i += stride) {
        float4 v = p[i];
        v.x = fmaxf(v.x, 0.0f); v.y = fmaxf(v.y, 0.0f);
        v.z = fmaxf(v.z, 0.0f); v.w = fmaxf(v.w, 0.0f);
        p[i] = v;
    }
}

// ---------------------------------------------------------------------------
static inline size_t align256(size_t x) { return (x + 255) & ~(size_t)255; }

extern "C" void kernel_launch(void* const* d_in, const int* in_sizes, int n_in,
                              void* d_out, int out_size, void* d_ws, size_t ws_size,
                              hipStream_t stream) {
    const float* x_vals   = (const float*)d_in[0];
    const float* kern     = (const float*)d_in[1];   // [256 x 128]
    const float* adj_vals = (const float*)d_in[2];
    const int*   x_rows   = (const int*)d_in[3];
    const int*   x_cols   = (const int*)d_in[4];
    const int*   adj_rows = (const int*)d_in[5];
    const int*   adj_cols = (const int*)d_in[6];
    const void*  mask     = d_in[7];

    const int nnz_x = in_sizes[0];
    const int nnz_a = in_sizes[2];
    const int n_nodes = out_size / O_DIM;
    const int ntot = 2 * n_nodes;
    const int nbuck = (ntot + BUCK_BINS - 1) / BUCK_BINS;
    const long long nnz_tot = (long long)nnz_x + nnz_a;
    const int B = (int)((nnz_tot + TILE - 1) / TILE);           // tiles
    const long long n_scan = (long long)nbuck * B;              // KxB matrix
    const int nb_scan = (int)((n_scan + SCAN_CHUNK - 1) / SCAN_CHUNK);

    float* out = (float*)d_out;
    char* ws = (char*)d_ws;

    // ---- ws carve-up: fixed buffers first, then PAD-dependent rec/packed ----
    size_t off = 0;
    int* flags = (int*)d_ws;            off = align256(off + 2 * sizeof(int));
    size_t o_k16 = off;                 off = align256(off + 256 * 128 * sizeof(half_t));
    size_t o_histT = off;               off = align256(off + (size_t)n_scan * 4);
    size_t o_tofs = off;                off = align256(off + ((size_t)n_scan + 1) * 4);
    size_t o_bsums = off;               off = align256(off + 4096 * 4);
    size_t o_S = off;                   off = align256(off + ((size_t)ntot + 1) * 4);
    size_t o_h = off;                   off = align256(off + (size_t)n_nodes * O_DIM * sizeof(half_t));
    const size_t fixed_end = off;

    // choose largest PAD in {8,4,2,1} whose worst-case rec+packed fit ws
    int PAD = 8;
    long long rec_cap = 0;
    while (true) {
        rec_cap = nnz_tot + (long long)(PAD - 1) * n_scan;   // worst-case records
        size_t need = fixed_end + 2 * align256((size_t)rec_cap * 8);
        if (need <= ws_size || PAD == 1) break;
        PAD >>= 1;
    }
    size_t o_rec = fixed_end;
    size_t o_packed = o_rec + align256((size_t)rec_cap * 8);
    size_t total_need = o_packed + align256((size_t)rec_cap * 8);

    const bool csr_ok = (total_need <= ws_size) && (nbuck <= 1024) &&
                        (n_nodes <= (1 << 17)) && (nb_scan <= 1024);

    // mask format detection (both paths need it)
    int scan_words = nnz_x / 4;
    if (scan_words > 16384) scan_words = 16384;
    detect_mask_kernel<<<1, 256, 0, stream>>>((const unsigned int*)mask, scan_words, flags);

    if (csr_ok) {
        half2_t* k16 = (half2_t*)(ws + o_k16);
        int*  histT  = (int*)(ws + o_histT);
        int*  tofs   = (int*)(ws + o_tofs);
        int*  bsums  = (int*)(ws + o_bsums);
        int*  S      = (int*)(ws + o_S);
        int2* rec    = (int2*)(ws + o_rec);
        int2* packed = (int2*)(ws + o_packed);
        half2_t* h2  = (half2_t*)(ws + o_h);

        // 0) kernel matrix -> f16 (16384 half2)
        conv_kern_kernel<<<64, 256, 0, stream>>>((const float2*)kern, k16, 16384);
        // A) per-tile bucket histograms (transposed, padded to PAD records)
        tile_hist_kernel<<<B, 256, 0, stream>>>(x_rows, nnz_x, adj_rows, nnz_a,
                                                n_nodes, nbuck, B, PAD, histT);
        // B) exclusive scan of the KxB matrix -> line-aligned chunk offsets
        scan_partial_kernel<<<nb_scan, SCAN_BS, 0, stream>>>(histT, (int)n_scan, bsums);
        scan_blocksums_kernel<<<1, 1024, 0, stream>>>(bsums, nb_scan,
                                                      &tofs[n_scan], &S[ntot]);
        scan_final_kernel<<<nb_scan, SCAN_BS, 0, stream>>>(histT, (int)n_scan, bsums, tofs);
        // C) multisplit: deterministic scatter + no-op pad fill
        multisplit_kernel<<<B, 256, 0, stream>>>(x_vals, x_rows, x_cols, mask, flags,
                                                 adj_vals, adj_rows, adj_cols,
                                                 nnz_x, nnz_a, n_nodes, nbuck, B,
                                                 tofs, rec);
        // D) per-bucket LDS counting sort -> packed + row_start S
        bucket_sort_kernel<<<nbuck, 256, 0, stream>>>(rec, tofs, B, ntot, packed, S);
        // E) SpMM1 (f16 weight gathers): h = dropout(X) @ kernel
        {
            int blocks = (n_nodes * 64 + 255) / 256;
            spmm1_wave_kernel<<<blocks, 256, 0, stream>>>(S, packed, k16, h2, n_nodes);
        }
        // F) SpMM2 + ReLU: out = relu(adj @ h)
        {
            int blocks = (n_nodes * 64 + 255) / 256;
            spmm2_wave_kernel<<<blocks, 256, 0, stream>>>(S + n_nodes, packed, h2,
                                                          (float2*)out, n_nodes);
        }
    } else {
        // ---- fallback: atomic path ----
        float* h = (float*)(ws + 256);
        hipMemsetAsync(h, 0, (size_t)n_nodes * O_DIM * 4, stream);
        hipMemsetAsync(out, 0, (size_t)out_size * 4, stream);
        {
            long long threads = (long long)nnz_x * O_DIM;
            int blocks = (int)((threads + 255) / 256);
            spmm1_atomic_kernel<<<blocks, 256, 0, stream>>>(x_vals, x_rows, x_cols, mask,
                                                            kern, flags, h, nnz_x);
            threads = (long long)nnz_a * O_DIM;
            blocks = (int)((threads + 255) / 256);
            spmm2_atomic_kernel<<<blocks, 256, 0, stream>>>(adj_vals, adj_rows, adj_cols,
                                                            h, out, nnz_a);
        }
        int n4 = out_size / 4;
        int blocks = (n4 + 255) / 256; if (blocks > 2048) blocks = 2048;
        relu_kernel<<<blocks, 256, 0, stream>>>(out, n4);
    }
}

// Round 10
// 243.016 us; speedup vs baseline: 1.2822x; 1.2822x over previous
//
#include <hip/hip_runtime.h>
#include <hip/hip_bf16.h>

// GraphSparseConvolution on MI355X.
// Round 10: pads are build-time-only. multisplit still pad-fills chunks to
// PAD records (line-exclusive writes, kills cross-XCD RMW), but pads carry
// col=0x1FFFF (impossible: col < n_nodes < 2^17). bucket_sort histograms
// and scatters REAL records only and emits exact per-row [S[r], E[r]) bounds
// (packed keeps a never-read gap at each bucket's tail). SpMMs process only
// real edges — round 9's +55% pad inflation in spmm1/2 is gone.
// Fallback to atomic path if ws too small.

static constexpr int O_DIM = 128;
static constexpr float KEEP_INV = 1.0f / 0.9f;  // 1/keep_prob
static constexpr int BUCK_BINS = 256;           // rows per coarse bucket
static constexpr int TILE = 4096;               // edges per multisplit tile
static constexpr unsigned PAD_COL = 0x1FFFFu;   // reserved pad marker column

using half_t = _Float16;
using half2_t = _Float16 __attribute__((ext_vector_type(2)));

// ---------------------------------------------------------------------------
// Detect how the harness materialized the bool keep_mask (int32/f32/uint8).
__global__ void detect_mask_kernel(const unsigned int* __restrict__ w, int nwords,
                                   int* __restrict__ flags) {
    __shared__ int sA[256];
    __shared__ int sB[256];
    int t = threadIdx.x;
    int violA = 0, violB = 0;
    for (int i = t; i < nwords; i += 256) {
        unsigned int x = w[i];
        violA |= (x > 1u) ? 1 : 0;
        violB |= (x != 0u && x != 0x3F800000u) ? 1 : 0;
    }
    sA[t] = violA; sB[t] = violB;
    __syncthreads();
    for (int s = 128; s > 0; s >>= 1) {
        if (t < s) { sA[t] |= sA[t + s]; sB[t] |= sB[t + s]; }
        __syncthreads();
    }
    if (t == 0) { flags[0] = sA[0]; flags[1] = sB[0]; }
}

// ---------------------------------------------------------------------------
// kernel matrix f32 -> f16 (once; 16384 half2).
__global__ void conv_kern_kernel(const float2* __restrict__ kern2,
                                 half2_t* __restrict__ k16, int n) {
    int i = blockIdx.x * 256 + threadIdx.x;
    if (i < n) {
        float2 v = kern2[i];
        half2_t o; o.x = (half_t)v.x; o.y = (half_t)v.y;
        k16[i] = o;
    }
}

// ---------------------------------------------------------------------------
// A) per-tile bucket histogram, PADDED to `pad` records per chunk, written
// transposed: histT[k*B + b].
__global__ __launch_bounds__(256) void tile_hist_kernel(
        const int* __restrict__ xr, int nnz_x,
        const int* __restrict__ ar, int nnz_a,
        int n_nodes, int nbuck, int B, int pad,
        int* __restrict__ histT) {
    __shared__ int hist[1024];
    int b = blockIdx.x, t = threadIdx.x;
    for (int k = t; k < 1024; k += 256) hist[k] = 0;
    __syncthreads();
    int tot = nnz_x + nnz_a;
    int tstart = b * TILE;
    int tend = min(tstart + TILE, tot);
    for (int i = tstart + t; i < tend; i += 256) {
        int bin = (i < nnz_x) ? xr[i] : (n_nodes + ar[i - nnz_x]);
        atomicAdd(&hist[bin >> 8], 1);
    }
    __syncthreads();
    int pm = pad - 1;
    for (int k = t; k < nbuck; k += 256)
        histT[(size_t)k * B + b] = (hist[k] + pm) & ~pm;
}

// ---------------------------------------------------------------------------
// 3-phase exclusive scan over cnt[0..n) -> S[0..n).
static constexpr int SCAN_BS = 256;
static constexpr int SCAN_IPT = 8;
static constexpr int SCAN_CHUNK = SCAN_BS * SCAN_IPT;  // 2048

__global__ __launch_bounds__(SCAN_BS) void scan_partial_kernel(const int* __restrict__ cnt,
                                                               int n, int* __restrict__ bsums) {
    int b = blockIdx.x, t = threadIdx.x;
    int lane = t & 63, wid = t >> 6;
    __shared__ int wsum[SCAN_BS / 64];
    int base = b * SCAN_CHUNK + t * SCAN_IPT;
    int s = 0;
    #pragma unroll
    for (int k = 0; k < SCAN_IPT; ++k) {
        int i = base + k;
        s += (i < n) ? cnt[i] : 0;
    }
    #pragma unroll
    for (int d = 1; d < 64; d <<= 1) s += __shfl_xor(s, d, 64);
    if (lane == 0) wsum[wid] = s;
    __syncthreads();
    if (t == 0) {
        int tot = 0;
        #pragma unroll
        for (int w = 0; w < SCAN_BS / 64; ++w) tot += wsum[w];
        bsums[b] = tot;
    }
}

__global__ __launch_bounds__(1024) void scan_blocksums_kernel(int* __restrict__ bsums, int nb,
                                                              int* __restrict__ sent0) {
    __shared__ int wsum[16];
    int t = threadIdx.x, lane = t & 63, wid = t >> 6;
    int v = (t < nb) ? bsums[t] : 0;
    int s = v;
    #pragma unroll
    for (int d = 1; d < 64; d <<= 1) {
        int u = __shfl_up(s, d, 64);
        if (lane >= d) s += u;
    }
    if (lane == 63) wsum[wid] = s;
    __syncthreads();
    int woff = 0;
    for (int w = 0; w < wid; ++w) woff += wsum[w];
    if (t < nb) bsums[t] = woff + s - v;      // exclusive
    if (t == 1023) *sent0 = woff + s;         // padded grand total
}

__global__ __launch_bounds__(SCAN_BS) void scan_final_kernel(const int* __restrict__ cnt, int n,
                                                             const int* __restrict__ bsums,
                                                             int* __restrict__ S) {
    __shared__ int wsum[SCAN_BS / 64];
    int b = blockIdx.x, t = threadIdx.x;
    int lane = t & 63, wid = t >> 6;
    int base = b * SCAN_CHUNK + t * SCAN_IPT;
    int v[SCAN_IPT];
    int tsum = 0;
    #pragma unroll
    for (int k = 0; k < SCAN_IPT; ++k) {
        int i = base + k;
        v[k] = (i < n) ? cnt[i] : 0;
        tsum += v[k];
    }
    int s = tsum;
    #pragma unroll
    for (int d = 1; d < 64; d <<= 1) {
        int u = __shfl_up(s, d, 64);
        if (lane >= d) s += u;
    }
    if (lane == 63) wsum[wid] = s;
    __syncthreads();
    int woff = 0;
    for (int w = 0; w < wid; ++w) woff += wsum[w];
    int excl = bsums[b] + woff + (s - tsum);
    #pragma unroll
    for (int k = 0; k < SCAN_IPT; ++k) {
        int i = base + k;
        if (i < n) S[i] = excl;
        excl += v[k];
    }
}

// ---------------------------------------------------------------------------
// C) multisplit: deterministic placement via LDS cursors seeded from tofs,
// then pad-fill each chunk's tail with marked no-op records (line-exclusive
// writes; pads are dropped by bucket_sort).
__global__ __launch_bounds__(256) void multisplit_kernel(
        const float* __restrict__ xv,
        const int* __restrict__ xr,
        const int* __restrict__ xc,
        const void* __restrict__ mask,
        const int* __restrict__ flags,
        const float* __restrict__ av,
        const int* __restrict__ ar,
        const int* __restrict__ ac,
        int nnz_x, int nnz_a, int n_nodes,
        int nbuck, int B,
        const int* __restrict__ tofs,
        int2* __restrict__ rec) {
    __shared__ int cur[1024];
    int b = blockIdx.x, t = threadIdx.x;
    for (int k = t; k < nbuck; k += 256)
        cur[k] = tofs[(size_t)k * B + b];
    __syncthreads();
    int tot = nnz_x + nnz_a;
    int tstart = b * TILE;
    int tend = min(tstart + TILE, tot);
    int f0 = flags[0], f1 = flags[1];
    for (int i = tstart + t; i < tend; i += 256) {
        int bin, col; float v;
        if (i < nnz_x) {
            bin = xr[i];
            col = xc[i];
            bool keep;
            if (f0 == 0)      keep = ((const int*)mask)[i] != 0;
            else if (f1 == 0) keep = ((const float*)mask)[i] != 0.0f;
            else              keep = ((const unsigned char*)mask)[i] != 0;
            v = keep ? xv[i] * KEEP_INV : 0.0f;
        } else {
            int e = i - nnz_x;
            bin = n_nodes + ar[e];
            col = ac[e];
            v = av[e];
        }
        int key = ((bin & (BUCK_BINS - 1)) << 17) | col;
        int pos = atomicAdd(&cur[bin >> 8], 1);   // LDS atomic — cheap
        rec[pos] = make_int2(key, __float_as_int(v));
    }
    __syncthreads();
    // pad-fill with marked records (col = PAD_COL -> dropped in bucket_sort)
    int fillkey = (int)((((unsigned)b & (BUCK_BINS - 1)) << 17) | PAD_COL);
    for (int k = t; k < nbuck; k += 256) {
        int fl = k * B + b;
        int pe = tofs[fl + 1];
        for (int p = cur[k]; p < pe; ++p)
            rec[p] = make_int2(fillkey, 0);
    }
}

// ---------------------------------------------------------------------------
// D) per-bucket LDS counting sort over REAL records -> packed + exact
// per-row [S, E) bounds. Pads are counted out; each bucket's packed region
// ends with a never-read gap.
__global__ __launch_bounds__(256) void bucket_sort_kernel(
        const int2* __restrict__ rec,
        const int* __restrict__ tofs, int B,
        int ntot, int2* __restrict__ packed,
        int* __restrict__ S, int* __restrict__ E) {
    __shared__ int hist[256];
    __shared__ int cur[256];
    __shared__ int wsum[4];
    int bb = blockIdx.x, t = threadIdx.x;
    int start = tofs[(size_t)bb * B];
    int end   = tofs[(size_t)(bb + 1) * B];
    hist[t] = 0;
    __syncthreads();
    for (int i = start + t; i < end; i += 256) {
        unsigned k = (unsigned)rec[i].x;
        if ((k & PAD_COL) != PAD_COL)
            atomicAdd(&hist[k >> 17], 1);
    }
    __syncthreads();
    int v = hist[t];
    int lane = t & 63, wid = t >> 6;
    int s = v;
    #pragma unroll
    for (int d = 1; d < 64; d <<= 1) {
        int u = __shfl_up(s, d, 64);
        if (lane >= d) s += u;
    }
    if (lane == 63) wsum[wid] = s;
    __syncthreads();
    int woff = 0;
    for (int w = 0; w < wid; ++w) woff += wsum[w];
    int excl = woff + s - v;
    int binBase = bb << 8;
    if (binBase + t < ntot) {
        S[binBase + t] = start + excl;
        E[binBase + t] = start + excl + v;
    }
    cur[t] = start + excl;
    __syncthreads();
    for (int i = start + t; i < end; i += 256) {
        int2 e = rec[i];
        unsigned k = (unsigned)e.x;
        if ((k & PAD_COL) == PAD_COL) continue;   // drop pads
        int pos = atomicAdd(&cur[k >> 17], 1);
        packed[pos] = make_int2((int)(k & PAD_COL), e.y);
    }
}

// ---------------------------------------------------------------------------
// E) SpMM1: wave-per-row, f16 weight gathers, int4 edge loads, 8-deep
// pipeline with 4-deep + scalar tails. src = k16 (half2), dst = h (f16x2).
__global__ __launch_bounds__(256) void spmm1_wave_kernel(
        const int* __restrict__ S, const int* __restrict__ E,
        const int2* __restrict__ packed,
        const half2_t* __restrict__ k16, half2_t* __restrict__ h2,
        int n_rows) {
    int gid = blockIdx.x * 256 + threadIdx.x;
    int r = gid >> 6;
    if (r >= n_rows) return;
    int lane = gid & 63;
    int j = S[r], end = E[r];
    float ax = 0.0f, ay = 0.0f;
    if ((j & 1) && j < end) {   // peel to 16B-align packed reads
        int2 e = packed[j];
        half2_t w = k16[e.x * 64 + lane];
        float v = __int_as_float(e.y);
        ax = fmaf(v, (float)w.x, ax); ay = fmaf(v, (float)w.y, ay);
        ++j;
    }
    for (; j + 8 <= end; j += 8) {
        int4 p0 = *(const int4*)(packed + j);
        int4 p1 = *(const int4*)(packed + j + 2);
        int4 p2 = *(const int4*)(packed + j + 4);
        int4 p3 = *(const int4*)(packed + j + 6);
        half2_t w0 = k16[p0.x * 64 + lane];
        half2_t w1 = k16[p0.z * 64 + lane];
        half2_t w2 = k16[p1.x * 64 + lane];
        half2_t w3 = k16[p1.z * 64 + lane];
        half2_t w4 = k16[p2.x * 64 + lane];
        half2_t w5 = k16[p2.z * 64 + lane];
        half2_t w6 = k16[p3.x * 64 + lane];
        half2_t w7 = k16[p3.z * 64 + lane];
        float v0 = __int_as_float(p0.y), v1 = __int_as_float(p0.w);
        float v2 = __int_as_float(p1.y), v3 = __int_as_float(p1.w);
        float v4 = __int_as_float(p2.y), v5 = __int_as_float(p2.w);
        float v6 = __int_as_float(p3.y), v7 = __int_as_float(p3.w);
        ax = fmaf(v0, (float)w0.x, ax); ay = fmaf(v0, (float)w0.y, ay);
        ax = fmaf(v1, (float)w1.x, ax); ay = fmaf(v1, (float)w1.y, ay);
        ax = fmaf(v2, (float)w2.x, ax); ay = fmaf(v2, (float)w2.y, ay);
        ax = fmaf(v3, (float)w3.x, ax); ay = fmaf(v3, (float)w3.y, ay);
        ax = fmaf(v4, (float)w4.x, ax); ay = fmaf(v4, (float)w4.y, ay);
        ax = fmaf(v5, (float)w5.x, ax); ay = fmaf(v5, (float)w5.y, ay);
        ax = fmaf(v6, (float)w6.x, ax); ay = fmaf(v6, (float)w6.y, ay);
        ax = fmaf(v7, (float)w7.x, ax); ay = fmaf(v7, (float)w7.y, ay);
    }
    if (j + 4 <= end) {
        int4 p0 = *(const int4*)(packed + j);
        int4 p1 = *(const int4*)(packed + j + 2);
        half2_t w0 = k16[p0.x * 64 + lane];
        half2_t w1 = k16[p0.z * 64 + lane];
        half2_t w2 = k16[p1.x * 64 + lane];
        half2_t w3 = k16[p1.z * 64 + lane];
        float v0 = __int_as_float(p0.y), v1 = __int_as_float(p0.w);
        float v2 = __int_as_float(p1.y), v3 = __int_as_float(p1.w);
        ax = fmaf(v0, (float)w0.x, ax); ay = fmaf(v0, (float)w0.y, ay);
        ax = fmaf(v1, (float)w1.x, ax); ay = fmaf(v1, (float)w1.y, ay);
        ax = fmaf(v2, (float)w2.x, ax); ay = fmaf(v2, (float)w2.y, ay);
        ax = fmaf(v3, (float)w3.x, ax); ay = fmaf(v3, (float)w3.y, ay);
        j += 4;
    }
    for (; j < end; ++j) {
        int2 e = packed[j];
        half2_t w = k16[e.x * 64 + lane];
        float v = __int_as_float(e.y);
        ax = fmaf(v, (float)w.x, ax); ay = fmaf(v, (float)w.y, ay);
    }
    half2_t o; o.x = (half_t)ax; o.y = (half_t)ay;
    h2[r * 64 + lane] = o;
}

// ---------------------------------------------------------------------------
// F) SpMM2 + ReLU: wave-per-row, 16-deep gather pipeline with 8/4/scalar
// tails, int4 edge loads.
__global__ __launch_bounds__(256) void spmm2_wave_kernel(
        const int* __restrict__ S, const int* __restrict__ E,
        const int2* __restrict__ packed,
        const half2_t* __restrict__ h2, float2* __restrict__ out2,
        int n_rows) {
    int gid = blockIdx.x * 256 + threadIdx.x;
    int r = gid >> 6;
    if (r >= n_rows) return;
    int lane = gid & 63;
    int j = S[r], end = E[r];
    float ax = 0.0f, ay = 0.0f;
    if ((j & 1) && j < end) {
        int2 e = packed[j];
        half2_t w = h2[e.x * 64 + lane];
        float v = __int_as_float(e.y);
        ax = fmaf(v, (float)w.x, ax); ay = fmaf(v, (float)w.y, ay);
        ++j;
    }
    for (; j + 16 <= end; j += 16) {
        int4 p0 = *(const int4*)(packed + j);
        int4 p1 = *(const int4*)(packed + j + 2);
        int4 p2 = *(const int4*)(packed + j + 4);
        int4 p3 = *(const int4*)(packed + j + 6);
        int4 p4 = *(const int4*)(packed + j + 8);
        int4 p5 = *(const int4*)(packed + j + 10);
        int4 p6 = *(const int4*)(packed + j + 12);
        int4 p7 = *(const int4*)(packed + j + 14);
        half2_t w0 = h2[p0.x * 64 + lane];
        half2_t w1 = h2[p0.z * 64 + lane];
        half2_t w2 = h2[p1.x * 64 + lane];
        half2_t w3 = h2[p1.z * 64 + lane];
        half2_t w4 = h2[p2.x * 64 + lane];
        half2_t w5 = h2[p2.z * 64 + lane];
        half2_t w6 = h2[p3.x * 64 + lane];
        half2_t w7 = h2[p3.z * 64 + lane];
        half2_t w8 = h2[p4.x * 64 + lane];
        half2_t w9 = h2[p4.z * 64 + lane];
        half2_t wa = h2[p5.x * 64 + lane];
        half2_t wb = h2[p5.z * 64 + lane];
        half2_t wc = h2[p6.x * 64 + lane];
        half2_t wd = h2[p6.z * 64 + lane];
        half2_t we = h2[p7.x * 64 + lane];
        half2_t wf = h2[p7.z * 64 + lane];
        float v0 = __int_as_float(p0.y), v1 = __int_as_float(p0.w);
        float v2 = __int_as_float(p1.y), v3 = __int_as_float(p1.w);
        float v4 = __int_as_float(p2.y), v5 = __int_as_float(p2.w);
        float v6 = __int_as_float(p3.y), v7 = __int_as_float(p3.w);
        float v8 = __int_as_float(p4.y), v9 = __int_as_float(p4.w);
        float va = __int_as_float(p5.y), vb = __int_as_float(p5.w);
        float vc = __int_as_float(p6.y), vd = __int_as_float(p6.w);
        float ve = __int_as_float(p7.y), vf = __int_as_float(p7.w);
        ax = fmaf(v0, (float)w0.x, ax); ay = fmaf(v0, (float)w0.y, ay);
        ax = fmaf(v1, (float)w1.x, ax); ay = fmaf(v1, (float)w1.y, ay);
        ax = fmaf(v2, (float)w2.x, ax); ay = fmaf(v2, (float)w2.y, ay);
        ax = fmaf(v3, (float)w3.x, ax); ay = fmaf(v3, (float)w3.y, ay);
        ax = fmaf(v4, (float)w4.x, ax); ay = fmaf(v4, (float)w4.y, ay);
        ax = fmaf(v5, (float)w5.x, ax); ay = fmaf(v5, (float)w5.y, ay);
        ax = fmaf(v6, (float)w6.x, ax); ay = fmaf(v6, (float)w6.y, ay);
        ax = fmaf(v7, (float)w7.x, ax); ay = fmaf(v7, (float)w7.y, ay);
        ax = fmaf(v8, (float)w8.x, ax); ay = fmaf(v8, (float)w8.y, ay);
        ax = fmaf(v9, (float)w9.x, ax); ay = fmaf(v9, (float)w9.y, ay);
        ax = fmaf(va, (float)wa.x, ax); ay = fmaf(va, (float)wa.y, ay);
        ax = fmaf(vb, (float)wb.x, ax); ay = fmaf(vb, (float)wb.y, ay);
        ax = fmaf(vc, (float)wc.x, ax); ay = fmaf(vc, (float)wc.y, ay);
        ax = fmaf(vd, (float)wd.x, ax); ay = fmaf(vd, (float)wd.y, ay);
        ax = fmaf(ve, (float)we.x, ax); ay = fmaf(ve, (float)we.y, ay);
        ax = fmaf(vf, (float)wf.x, ax); ay = fmaf(vf, (float)wf.y, ay);
    }
    if (j + 8 <= end) {
        int4 p0 = *(const int4*)(packed + j);
        int4 p1 = *(const int4*)(packed + j + 2);
        int4 p2 = *(const int4*)(packed + j + 4);
        int4 p3 = *(const int4*)(packed + j + 6);
        half2_t w0 = h2[p0.x * 64 + lane];
        half2_t w1 = h2[p0.z * 64 + lane];
        half2_t w2 = h2[p1.x * 64 + lane];
        half2_t w3 = h2[p1.z * 64 + lane];
        half2_t w4 = h2[p2.x * 64 + lane];
        half2_t w5 = h2[p2.z * 64 + lane];
        half2_t w6 = h2[p3.x * 64 + lane];
        half2_t w7 = h2[p3.z * 64 + lane];
        float v0 = __int_as_float(p0.y), v1 = __int_as_float(p0.w);
        float v2 = __int_as_float(p1.y), v3 = __int_as_float(p1.w);
        float v4 = __int_as_float(p2.y), v5 = __int_as_float(p2.w);
        float v6 = __int_as_float(p3.y), v7 = __int_as_float(p3.w);
        ax = fmaf(v0, (float)w0.x, ax); ay = fmaf(v0, (float)w0.y, ay);
        ax = fmaf(v1, (float)w1.x, ax); ay = fmaf(v1, (float)w1.y, ay);
        ax = fmaf(v2, (float)w2.x, ax); ay = fmaf(v2, (float)w2.y, ay);
        ax = fmaf(v3, (float)w3.x, ax); ay = fmaf(v3, (float)w3.y, ay);
        ax = fmaf(v4, (float)w4.x, ax); ay = fmaf(v4, (float)w4.y, ay);
        ax = fmaf(v5, (float)w5.x, ax); ay = fmaf(v5, (float)w5.y, ay);
        ax = fmaf(v6, (float)w6.x, ax); ay = fmaf(v6, (float)w6.y, ay);
        ax = fmaf(v7, (float)w7.x, ax); ay = fmaf(v7, (float)w7.y, ay);
        j += 8;
    }
    if (j + 4 <= end) {
        int4 p0 = *(const int4*)(packed + j);
        int4 p1 = *(const int4*)(packed + j + 2);
        half2_t w0 = h2[p0.x * 64 + lane];
        half2_t w1 = h2[p0.z * 64 + lane];
        half2_t w2 = h2[p1.x * 64 + lane];
        half2_t w3 = h2[p1.z * 64 + lane];
        float v0 = __int_as_float(p0.y), v1 = __int_as_float(p0.w);
        float v2 = __int_as_float(p1.y), v3 = __int_as_float(p1.w);
        ax = fmaf(v0, (float)w0.x, ax); ay = fmaf(v0, (float)w0.y, ay);
        ax = fmaf(v1, (float)w1.x, ax); ay = fmaf(v1, (float)w1.y, ay);
        ax = fmaf(v2, (float)w2.x, ax); ay = fmaf(v2, (float)w2.y, ay);
        ax = fmaf(v3, (float)w3.x, ax); ay = fmaf(v3, (float)w3.y, ay);
        j += 4;
    }
    for (; j < end; ++j) {
        int2 e = packed[j];
        half2_t w = h2[e.x * 64 + lane];
        float v = __int_as_float(e.y);
        ax = fmaf(v, (float)w.x, ax); ay = fmaf(v, (float)w.y, ay);
    }
    out2[r * 64 + lane] = make_float2(fmaxf(ax, 0.0f), fmaxf(ay, 0.0f));
}

// ---------------------------------------------------------------------------
// Fallback atomic path (only if ws too small).
__global__ void spmm1_atomic_kernel(const float* __restrict__ xv,
                                    const int* __restrict__ xr,
                                    const int* __restrict__ xc,
                                    const void* __restrict__ mask,
                                    const float* __restrict__ kern,
                                    const int* __restrict__ flags,
                                    float* __restrict__ h, int nnz) {
    long long gid = (long long)blockIdx.x * blockDim.x + threadIdx.x;
    int e = (int)(gid >> 7);
    if (e >= nnz) return;
    int o = (int)(gid & 127);
    bool keep;
    if (flags[0] == 0)      keep = ((const int*)mask)[e] != 0;
    else if (flags[1] == 0) keep = ((const float*)mask)[e] != 0.0f;
    else                    keep = ((const unsigned char*)mask)[e] != 0;
    if (!keep) return;
    atomicAdd(&h[(long long)xr[e] * O_DIM + o], xv[e] * KEEP_INV * kern[xc[e] * O_DIM + o]);
}

__global__ void spmm2_atomic_kernel(const float* __restrict__ av,
                                    const int* __restrict__ ar,
                                    const int* __restrict__ ac,
                                    const float* __restrict__ h,
                                    float* __restrict__ out, int nnz) {
    long long gid = (long long)blockIdx.x * blockDim.x + threadIdx.x;
    int e = (int)(gid >> 7);
    if (e >= nnz) return;
    int o = (int)(gid & 127);
    atomicAdd(&out[(long long)ar[e] * O_DIM + o], av[e] * h[(long long)ac[e] * O_DIM + o]);
}

__global__ void relu_kernel(float* __restrict__ out, int n4) {
    int stride = gridDim.x * blockDim.x;
    float4* p = (float4*)out;
    for (int i = blockIdx.x * blockDim.x + threadIdx.x; i < n4; i += stride) {
        float4 v = p[i];
        v.x = fmaxf(v.x, 0.0f); v.y = fmaxf(v.y, 0.0f);
        v.z = fmaxf(v.z, 0.0f); v.w = fmaxf(v.w, 0.0f);
        p[i] = v;
    }
}

// ---------------------------------------------------------------------------
static inline size_t align256(size_t x) { return (x + 255) & ~(size_t)255; }

extern "C" void kernel_launch(void* const* d_in, const int* in_sizes, int n_in,
                              void* d_out, int out_size, void* d_ws, size_t ws_size,
                              hipStream_t stream) {
    const float* x_vals   = (const float*)d_in[0];
    const float* kern     = (const float*)d_in[1];   // [256 x 128]
    const float* adj_vals = (const float*)d_in[2];
    const int*   x_rows   = (const int*)d_in[3];
    const int*   x_cols   = (const int*)d_in[4];
    const int*   adj_rows = (const int*)d_in[5];
    const int*   adj_cols = (const int*)d_in[6];
    const void*  mask     = d_in[7];

    const int nnz_x = in_sizes[0];
    const int nnz_a = in_sizes[2];
    const int n_nodes = out_size / O_DIM;
    const int ntot = 2 * n_nodes;
    const int nbuck = (ntot + BUCK_BINS - 1) / BUCK_BINS;
    const long long nnz_tot = (long long)nnz_x + nnz_a;
    const int B = (int)((nnz_tot + TILE - 1) / TILE);           // tiles
    const long long n_scan = (long long)nbuck * B;              // KxB matrix
    const int nb_scan = (int)((n_scan + SCAN_CHUNK - 1) / SCAN_CHUNK);

    float* out = (float*)d_out;
    char* ws = (char*)d_ws;

    // ---- ws carve-up: fixed buffers first, then PAD-dependent rec/packed ----
    size_t off = 0;
    int* flags = (int*)d_ws;            off = align256(off + 2 * sizeof(int));
    size_t o_k16 = off;                 off = align256(off + 256 * 128 * sizeof(half_t));
    size_t o_histT = off;               off = align256(off + (size_t)n_scan * 4);
    size_t o_tofs = off;                off = align256(off + ((size_t)n_scan + 1) * 4);
    size_t o_bsums = off;               off = align256(off + 4096 * 4);
    size_t o_S = off;                   off = align256(off + ((size_t)ntot + 1) * 4);
    size_t o_E = off;                   off = align256(off + (size_t)ntot * 4);
    size_t o_h = off;                   off = align256(off + (size_t)n_nodes * O_DIM * sizeof(half_t));
    const size_t fixed_end = off;

    // choose largest PAD in {8,4,2,1} whose worst-case rec+packed fit ws
    int PAD = 8;
    long long rec_cap = 0;
    while (true) {
        rec_cap = nnz_tot + (long long)(PAD - 1) * n_scan;   // worst-case records
        size_t need = fixed_end + 2 * align256((size_t)rec_cap * 8);
        if (need <= ws_size || PAD == 1) break;
        PAD >>= 1;
    }
    size_t o_rec = fixed_end;
    size_t o_packed = o_rec + align256((size_t)rec_cap * 8);
    size_t total_need = o_packed + align256((size_t)rec_cap * 8);

    const bool csr_ok = (total_need <= ws_size) && (nbuck <= 1024) &&
                        (n_nodes < (1 << 17)) && (nb_scan <= 1024);

    // mask format detection (both paths need it)
    int scan_words = nnz_x / 4;
    if (scan_words > 16384) scan_words = 16384;
    detect_mask_kernel<<<1, 256, 0, stream>>>((const unsigned int*)mask, scan_words, flags);

    if (csr_ok) {
        half2_t* k16 = (half2_t*)(ws + o_k16);
        int*  histT  = (int*)(ws + o_histT);
        int*  tofs   = (int*)(ws + o_tofs);
        int*  bsums  = (int*)(ws + o_bsums);
        int*  S      = (int*)(ws + o_S);
        int*  E      = (int*)(ws + o_E);
        int2* rec    = (int2*)(ws + o_rec);
        int2* packed = (int2*)(ws + o_packed);
        half2_t* h2  = (half2_t*)(ws + o_h);

        // 0) kernel matrix -> f16 (16384 half2)
        conv_kern_kernel<<<64, 256, 0, stream>>>((const float2*)kern, k16, 16384);
        // A) per-tile bucket histograms (transposed, padded to PAD records)
        tile_hist_kernel<<<B, 256, 0, stream>>>(x_rows, nnz_x, adj_rows, nnz_a,
                                                n_nodes, nbuck, B, PAD, histT);
        // B) exclusive scan of the KxB matrix -> line-aligned chunk offsets
        scan_partial_kernel<<<nb_scan, SCAN_BS, 0, stream>>>(histT, (int)n_scan, bsums);
        scan_blocksums_kernel<<<1, 1024, 0, stream>>>(bsums, nb_scan, &tofs[n_scan]);
        scan_final_kernel<<<nb_scan, SCAN_BS, 0, stream>>>(histT, (int)n_scan, bsums, tofs);
        // C) multisplit: deterministic scatter + marked pad fill
        multisplit_kernel<<<B, 256, 0, stream>>>(x_vals, x_rows, x_cols, mask, flags,
                                                 adj_vals, adj_rows, adj_cols,
                                                 nnz_x, nnz_a, n_nodes, nbuck, B,
                                                 tofs, rec);
        // D) per-bucket counting sort (drops pads) -> packed + exact [S,E)
        bucket_sort_kernel<<<nbuck, 256, 0, stream>>>(rec, tofs, B, ntot, packed, S, E);
        // E) SpMM1 (f16 weight gathers): h = dropout(X) @ kernel
        {
            int blocks = (n_nodes * 64 + 255) / 256;
            spmm1_wave_kernel<<<blocks, 256, 0, stream>>>(S, E, packed, k16, h2, n_nodes);
        }
        // F) SpMM2 + ReLU: out = relu(adj @ h)
        {
            int blocks = (n_nodes * 64 + 255) / 256;
            spmm2_wave_kernel<<<blocks, 256, 0, stream>>>(S + n_nodes, E + n_nodes,
                                                          packed, h2, (float2*)out, n_nodes);
        }
    } else {
        // ---- fallback: atomic path ----
        float* h = (float*)(ws + 256);
        hipMemsetAsync(h, 0, (size_t)n_nodes * O_DIM * 4, stream);
        hipMemsetAsync(out, 0, (size_t)out_size * 4, stream);
        {
            long long threads = (long long)nnz_x * O_DIM;
            int blocks = (int)((threads + 255) / 256);
            spmm1_atomic_kernel<<<blocks, 256, 0, stream>>>(x_vals, x_rows, x_cols, mask,
                                                            kern, flags, h, nnz_x);
            threads = (long long)nnz_a * O_DIM;
            blocks = (int)((threads + 255) / 256);
            spmm2_atomic_kernel<<<blocks, 256, 0, stream>>>(adj_vals, adj_rows, adj_cols,
                                                            h, out, nnz_a);
        }
        int n4 = out_size / 4;
        int blocks = (n4 + 255) / 256; if (blocks > 2048) blocks = 2048;
        relu_kernel<<<blocks, 256, 0, stream>>>(out, n4);
    }
}

// Round 11
// 234.068 us; speedup vs baseline: 1.3312x; 1.0382x over previous
//
#include <hip/hip_runtime.h>
#include <hip/hip_bf16.h>

// GraphSparseConvolution on MI355X.
// Round 11: multisplit/tile_hist go to 512-thread blocks (8 waves/block,
// ~24 waves/CU) with fully batched register-preloaded iterations (32 loads
// in flight/thread) — attacks multisplit's 24%-occupancy latency bound.
// Build layout (PAD-marked line-exclusive chunks, bucket_sort drops pads,
// exact [S,E) row bounds) unchanged from round 10.
// Fallback to atomic path if ws too small.

static constexpr int O_DIM = 128;
static constexpr float KEEP_INV = 1.0f / 0.9f;  // 1/keep_prob
static constexpr int BUCK_BINS = 256;           // rows per coarse bucket
static constexpr int TILE = 4096;               // edges per multisplit tile
static constexpr int MS_THREADS = 512;          // threads per build block
static constexpr int MS_ITER = TILE / MS_THREADS;   // 8
static constexpr unsigned PAD_COL = 0x1FFFFu;   // reserved pad marker column

using half_t = _Float16;
using half2_t = _Float16 __attribute__((ext_vector_type(2)));

// ---------------------------------------------------------------------------
// Detect how the harness materialized the bool keep_mask (int32/f32/uint8).
__global__ void detect_mask_kernel(const unsigned int* __restrict__ w, int nwords,
                                   int* __restrict__ flags) {
    __shared__ int sA[256];
    __shared__ int sB[256];
    int t = threadIdx.x;
    int violA = 0, violB = 0;
    for (int i = t; i < nwords; i += 256) {
        unsigned int x = w[i];
        violA |= (x > 1u) ? 1 : 0;
        violB |= (x != 0u && x != 0x3F800000u) ? 1 : 0;
    }
    sA[t] = violA; sB[t] = violB;
    __syncthreads();
    for (int s = 128; s > 0; s >>= 1) {
        if (t < s) { sA[t] |= sA[t + s]; sB[t] |= sB[t + s]; }
        __syncthreads();
    }
    if (t == 0) { flags[0] = sA[0]; flags[1] = sB[0]; }
}

// ---------------------------------------------------------------------------
// kernel matrix f32 -> f16 (once; 16384 half2).
__global__ void conv_kern_kernel(const float2* __restrict__ kern2,
                                 half2_t* __restrict__ k16, int n) {
    int i = blockIdx.x * 256 + threadIdx.x;
    if (i < n) {
        float2 v = kern2[i];
        half2_t o; o.x = (half_t)v.x; o.y = (half_t)v.y;
        k16[i] = o;
    }
}

// ---------------------------------------------------------------------------
// A) per-tile bucket histogram, PADDED to `pad` records per chunk, written
// transposed: histT[k*B + b]. 512 threads, batched loads.
__global__ __launch_bounds__(MS_THREADS) void tile_hist_kernel(
        const int* __restrict__ xr, int nnz_x,
        const int* __restrict__ ar, int nnz_a,
        int n_nodes, int nbuck, int B, int pad,
        int* __restrict__ histT) {
    __shared__ int hist[1024];
    int b = blockIdx.x, t = threadIdx.x;
    for (int k = t; k < 1024; k += MS_THREADS) hist[k] = 0;
    __syncthreads();
    int tot = nnz_x + nnz_a;
    int tstart = b * TILE;
    int tend = min(tstart + TILE, tot);
    int bin[MS_ITER];
    #pragma unroll
    for (int u = 0; u < MS_ITER; ++u) {
        int i = tstart + t + u * MS_THREADS;
        bin[u] = (i < tend) ? ((i < nnz_x) ? xr[i] : (n_nodes + ar[i - nnz_x])) : -1;
    }
    #pragma unroll
    for (int u = 0; u < MS_ITER; ++u)
        if (bin[u] >= 0) atomicAdd(&hist[bin[u] >> 8], 1);
    __syncthreads();
    int pm = pad - 1;
    for (int k = t; k < nbuck; k += MS_THREADS)
        histT[(size_t)k * B + b] = (hist[k] + pm) & ~pm;
}

// ---------------------------------------------------------------------------
// 3-phase exclusive scan over cnt[0..n) -> S[0..n).
static constexpr int SCAN_BS = 256;
static constexpr int SCAN_IPT = 8;
static constexpr int SCAN_CHUNK = SCAN_BS * SCAN_IPT;  // 2048

__global__ __launch_bounds__(SCAN_BS) void scan_partial_kernel(const int* __restrict__ cnt,
                                                               int n, int* __restrict__ bsums) {
    int b = blockIdx.x, t = threadIdx.x;
    int lane = t & 63, wid = t >> 6;
    __shared__ int wsum[SCAN_BS / 64];
    int base = b * SCAN_CHUNK + t * SCAN_IPT;
    int s = 0;
    #pragma unroll
    for (int k = 0; k < SCAN_IPT; ++k) {
        int i = base + k;
        s += (i < n) ? cnt[i] : 0;
    }
    #pragma unroll
    for (int d = 1; d < 64; d <<= 1) s += __shfl_xor(s, d, 64);
    if (lane == 0) wsum[wid] = s;
    __syncthreads();
    if (t == 0) {
        int tot = 0;
        #pragma unroll
        for (int w = 0; w < SCAN_BS / 64; ++w) tot += wsum[w];
        bsums[b] = tot;
    }
}

__global__ __launch_bounds__(1024) void scan_blocksums_kernel(int* __restrict__ bsums, int nb,
                                                              int* __restrict__ sent0) {
    __shared__ int wsum[16];
    int t = threadIdx.x, lane = t & 63, wid = t >> 6;
    int v = (t < nb) ? bsums[t] : 0;
    int s = v;
    #pragma unroll
    for (int d = 1; d < 64; d <<= 1) {
        int u = __shfl_up(s, d, 64);
        if (lane >= d) s += u;
    }
    if (lane == 63) wsum[wid] = s;
    __syncthreads();
    int woff = 0;
    for (int w = 0; w < wid; ++w) woff += wsum[w];
    if (t < nb) bsums[t] = woff + s - v;      // exclusive
    if (t == 1023) *sent0 = woff + s;         // padded grand total
}

__global__ __launch_bounds__(SCAN_BS) void scan_final_kernel(const int* __restrict__ cnt, int n,
                                                             const int* __restrict__ bsums,
                                                             int* __restrict__ S) {
    __shared__ int wsum[SCAN_BS / 64];
    int b = blockIdx.x, t = threadIdx.x;
    int lane = t & 63, wid = t >> 6;
    int base = b * SCAN_CHUNK + t * SCAN_IPT;
    int v[SCAN_IPT];
    int tsum = 0;
    #pragma unroll
    for (int k = 0; k < SCAN_IPT; ++k) {
        int i = base + k;
        v[k] = (i < n) ? cnt[i] : 0;
        tsum += v[k];
    }
    int s = tsum;
    #pragma unroll
    for (int d = 1; d < 64; d <<= 1) {
        int u = __shfl_up(s, d, 64);
        if (lane >= d) s += u;
    }
    if (lane == 63) wsum[wid] = s;
    __syncthreads();
    int woff = 0;
    for (int w = 0; w < wid; ++w) woff += wsum[w];
    int excl = bsums[b] + woff + (s - tsum);
    #pragma unroll
    for (int k = 0; k < SCAN_IPT; ++k) {
        int i = base + k;
        if (i < n) S[i] = excl;
        excl += v[k];
    }
}

// ---------------------------------------------------------------------------
// C) multisplit: deterministic placement via LDS cursors seeded from tofs.
// 512 threads; all MS_ITER iterations' inputs preloaded into registers
// (32 loads in flight/thread), then the atomic+store chain runs.
// Pad-fill with marked records at the end (line-exclusive writes).
__global__ __launch_bounds__(MS_THREADS) void multisplit_kernel(
        const float* __restrict__ xv,
        const int* __restrict__ xr,
        const int* __restrict__ xc,
        const void* __restrict__ mask,
        const int* __restrict__ flags,
        const float* __restrict__ av,
        const int* __restrict__ ar,
        const int* __restrict__ ac,
        int nnz_x, int nnz_a, int n_nodes,
        int nbuck, int B,
        const int* __restrict__ tofs,
        int2* __restrict__ rec) {
    __shared__ int cur[1024];
    int b = blockIdx.x, t = threadIdx.x;
    for (int k = t; k < nbuck; k += MS_THREADS)
        cur[k] = tofs[(size_t)k * B + b];
    __syncthreads();
    int tot = nnz_x + nnz_a;
    int tstart = b * TILE;
    int tend = min(tstart + TILE, tot);
    int f0 = flags[0], f1 = flags[1];

    int bin[MS_ITER], col[MS_ITER];
    float val[MS_ITER];
    #pragma unroll
    for (int u = 0; u < MS_ITER; ++u) {
        int i = tstart + t + u * MS_THREADS;
        bin[u] = -1;
        if (i < tend) {
            if (i < nnz_x) {
                bin[u] = xr[i];
                col[u] = xc[i];
                bool keep;
                if (f0 == 0)      keep = ((const int*)mask)[i] != 0;
                else if (f1 == 0) keep = ((const float*)mask)[i] != 0.0f;
                else              keep = ((const unsigned char*)mask)[i] != 0;
                val[u] = keep ? xv[i] * KEEP_INV : 0.0f;
            } else {
                int e = i - nnz_x;
                bin[u] = n_nodes + ar[e];
                col[u] = ac[e];
                val[u] = av[e];
            }
        }
    }
    #pragma unroll
    for (int u = 0; u < MS_ITER; ++u) {
        if (bin[u] >= 0) {
            int key = ((bin[u] & (BUCK_BINS - 1)) << 17) | col[u];
            int pos = atomicAdd(&cur[bin[u] >> 8], 1);   // LDS atomic — cheap
            rec[pos] = make_int2(key, __float_as_int(val[u]));
        }
    }
    __syncthreads();
    // pad-fill with marked records (col = PAD_COL -> dropped in bucket_sort)
    int fillkey = (int)((((unsigned)b & (BUCK_BINS - 1)) << 17) | PAD_COL);
    for (int k = t; k < nbuck; k += MS_THREADS) {
        int fl = k * B + b;
        int pe = tofs[fl + 1];
        for (int p = cur[k]; p < pe; ++p)
            rec[p] = make_int2(fillkey, 0);
    }
}

// ---------------------------------------------------------------------------
// D) per-bucket LDS counting sort over REAL records -> packed + exact
// per-row [S, E) bounds. Pads are counted out; each bucket's packed region
// ends with a never-read gap.
__global__ __launch_bounds__(256) void bucket_sort_kernel(
        const int2* __restrict__ rec,
        const int* __restrict__ tofs, int B,
        int ntot, int2* __restrict__ packed,
        int* __restrict__ S, int* __restrict__ E) {
    __shared__ int hist[256];
    __shared__ int cur[256];
    __shared__ int wsum[4];
    int bb = blockIdx.x, t = threadIdx.x;
    int start = tofs[(size_t)bb * B];
    int end   = tofs[(size_t)(bb + 1) * B];
    hist[t] = 0;
    __syncthreads();
    for (int i = start + t; i < end; i += 256) {
        unsigned k = (unsigned)rec[i].x;
        if ((k & PAD_COL) != PAD_COL)
            atomicAdd(&hist[k >> 17], 1);
    }
    __syncthreads();
    int v = hist[t];
    int lane = t & 63, wid = t >> 6;
    int s = v;
    #pragma unroll
    for (int d = 1; d < 64; d <<= 1) {
        int u = __shfl_up(s, d, 64);
        if (lane >= d) s += u;
    }
    if (lane == 63) wsum[wid] = s;
    __syncthreads();
    int woff = 0;
    for (int w = 0; w < wid; ++w) woff += wsum[w];
    int excl = woff + s - v;
    int binBase = bb << 8;
    if (binBase + t < ntot) {
        S[binBase + t] = start + excl;
        E[binBase + t] = start + excl + v;
    }
    cur[t] = start + excl;
    __syncthreads();
    for (int i = start + t; i < end; i += 256) {
        int2 e = rec[i];
        unsigned k = (unsigned)e.x;
        if ((k & PAD_COL) == PAD_COL) continue;   // drop pads
        int pos = atomicAdd(&cur[k >> 17], 1);
        packed[pos] = make_int2((int)(k & PAD_COL), e.y);
    }
}

// ---------------------------------------------------------------------------
// E) SpMM1: wave-per-row, f16 weight gathers, int4 edge loads, 8-deep
// pipeline with 4-deep + scalar tails. src = k16 (half2), dst = h (f16x2).
__global__ __launch_bounds__(256) void spmm1_wave_kernel(
        const int* __restrict__ S, const int* __restrict__ E,
        const int2* __restrict__ packed,
        const half2_t* __restrict__ k16, half2_t* __restrict__ h2,
        int n_rows) {
    int gid = blockIdx.x * 256 + threadIdx.x;
    int r = gid >> 6;
    if (r >= n_rows) return;
    int lane = gid & 63;
    int j = S[r], end = E[r];
    float ax = 0.0f, ay = 0.0f;
    if ((j & 1) && j < end) {   // peel to 16B-align packed reads
        int2 e = packed[j];
        half2_t w = k16[e.x * 64 + lane];
        float v = __int_as_float(e.y);
        ax = fmaf(v, (float)w.x, ax); ay = fmaf(v, (float)w.y, ay);
        ++j;
    }
    for (; j + 8 <= end; j += 8) {
        int4 p0 = *(const int4*)(packed + j);
        int4 p1 = *(const int4*)(packed + j + 2);
        int4 p2 = *(const int4*)(packed + j + 4);
        int4 p3 = *(const int4*)(packed + j + 6);
        half2_t w0 = k16[p0.x * 64 + lane];
        half2_t w1 = k16[p0.z * 64 + lane];
        half2_t w2 = k16[p1.x * 64 + lane];
        half2_t w3 = k16[p1.z * 64 + lane];
        half2_t w4 = k16[p2.x * 64 + lane];
        half2_t w5 = k16[p2.z * 64 + lane];
        half2_t w6 = k16[p3.x * 64 + lane];
        half2_t w7 = k16[p3.z * 64 + lane];
        float v0 = __int_as_float(p0.y), v1 = __int_as_float(p0.w);
        float v2 = __int_as_float(p1.y), v3 = __int_as_float(p1.w);
        float v4 = __int_as_float(p2.y), v5 = __int_as_float(p2.w);
        float v6 = __int_as_float(p3.y), v7 = __int_as_float(p3.w);
        ax = fmaf(v0, (float)w0.x, ax); ay = fmaf(v0, (float)w0.y, ay);
        ax = fmaf(v1, (float)w1.x, ax); ay = fmaf(v1, (float)w1.y, ay);
        ax = fmaf(v2, (float)w2.x, ax); ay = fmaf(v2, (float)w2.y, ay);
        ax = fmaf(v3, (float)w3.x, ax); ay = fmaf(v3, (float)w3.y, ay);
        ax = fmaf(v4, (float)w4.x, ax); ay = fmaf(v4, (float)w4.y, ay);
        ax = fmaf(v5, (float)w5.x, ax); ay = fmaf(v5, (float)w5.y, ay);
        ax = fmaf(v6, (float)w6.x, ax); ay = fmaf(v6, (float)w6.y, ay);
        ax = fmaf(v7, (float)w7.x, ax); ay = fmaf(v7, (float)w7.y, ay);
    }
    if (j + 4 <= end) {
        int4 p0 = *(const int4*)(packed + j);
        int4 p1 = *(const int4*)(packed + j + 2);
        half2_t w0 = k16[p0.x * 64 + lane];
        half2_t w1 = k16[p0.z * 64 + lane];
        half2_t w2 = k16[p1.x * 64 + lane];
        half2_t w3 = k16[p1.z * 64 + lane];
        float v0 = __int_as_float(p0.y), v1 = __int_as_float(p0.w);
        float v2 = __int_as_float(p1.y), v3 = __int_as_float(p1.w);
        ax = fmaf(v0, (float)w0.x, ax); ay = fmaf(v0, (float)w0.y, ay);
        ax = fmaf(v1, (float)w1.x, ax); ay = fmaf(v1, (float)w1.y, ay);
        ax = fmaf(v2, (float)w2.x, ax); ay = fmaf(v2, (float)w2.y, ay);
        ax = fmaf(v3, (float)w3.x, ax); ay = fmaf(v3, (float)w3.y, ay);
        j += 4;
    }
    for (; j < end; ++j) {
        int2 e = packed[j];
        half2_t w = k16[e.x * 64 + lane];
        float v = __int_as_float(e.y);
        ax = fmaf(v, (float)w.x, ax); ay = fmaf(v, (float)w.y, ay);
    }
    half2_t o; o.x = (half_t)ax; o.y = (half_t)ay;
    h2[r * 64 + lane] = o;
}

// ---------------------------------------------------------------------------
// F) SpMM2 + ReLU: wave-per-row, 16-deep gather pipeline with 8/4/scalar
// tails, int4 edge loads.
__global__ __launch_bounds__(256) void spmm2_wave_kernel(
        const int* __restrict__ S, const int* __restrict__ E,
        const int2* __restrict__ packed,
        const half2_t* __restrict__ h2, float2* __restrict__ out2,
        int n_rows) {
    int gid = blockIdx.x * 256 + threadIdx.x;
    int r = gid >> 6;
    if (r >= n_rows) return;
    int lane = gid & 63;
    int j = S[r], end = E[r];
    float ax = 0.0f, ay = 0.0f;
    if ((j & 1) && j < end) {
        int2 e = packed[j];
        half2_t w = h2[e.x * 64 + lane];
        float v = __int_as_float(e.y);
        ax = fmaf(v, (float)w.x, ax); ay = fmaf(v, (float)w.y, ay);
        ++j;
    }
    for (; j + 16 <= end; j += 16) {
        int4 p0 = *(const int4*)(packed + j);
        int4 p1 = *(const int4*)(packed + j + 2);
        int4 p2 = *(const int4*)(packed + j + 4);
        int4 p3 = *(const int4*)(packed + j + 6);
        int4 p4 = *(const int4*)(packed + j + 8);
        int4 p5 = *(const int4*)(packed + j + 10);
        int4 p6 = *(const int4*)(packed + j + 12);
        int4 p7 = *(const int4*)(packed + j + 14);
        half2_t w0 = h2[p0.x * 64 + lane];
        half2_t w1 = h2[p0.z * 64 + lane];
        half2_t w2 = h2[p1.x * 64 + lane];
        half2_t w3 = h2[p1.z * 64 + lane];
        half2_t w4 = h2[p2.x * 64 + lane];
        half2_t w5 = h2[p2.z * 64 + lane];
        half2_t w6 = h2[p3.x * 64 + lane];
        half2_t w7 = h2[p3.z * 64 + lane];
        half2_t w8 = h2[p4.x * 64 + lane];
        half2_t w9 = h2[p4.z * 64 + lane];
        half2_t wa = h2[p5.x * 64 + lane];
        half2_t wb = h2[p5.z * 64 + lane];
        half2_t wc = h2[p6.x * 64 + lane];
        half2_t wd = h2[p6.z * 64 + lane];
        half2_t we = h2[p7.x * 64 + lane];
        half2_t wf = h2[p7.z * 64 + lane];
        float v0 = __int_as_float(p0.y), v1 = __int_as_float(p0.w);
        float v2 = __int_as_float(p1.y), v3 = __int_as_float(p1.w);
        float v4 = __int_as_float(p2.y), v5 = __int_as_float(p2.w);
        float v6 = __int_as_float(p3.y), v7 = __int_as_float(p3.w);
        float v8 = __int_as_float(p4.y), v9 = __int_as_float(p4.w);
        float va = __int_as_float(p5.y), vb = __int_as_float(p5.w);
        float vc = __int_as_float(p6.y), vd = __int_as_float(p6.w);
        float ve = __int_as_float(p7.y), vf = __int_as_float(p7.w);
        ax = fmaf(v0, (float)w0.x, ax); ay = fmaf(v0, (float)w0.y, ay);
        ax = fmaf(v1, (float)w1.x, ax); ay = fmaf(v1, (float)w1.y, ay);
        ax = fmaf(v2, (float)w2.x, ax); ay = fmaf(v2, (float)w2.y, ay);
        ax = fmaf(v3, (float)w3.x, ax); ay = fmaf(v3, (float)w3.y, ay);
        ax = fmaf(v4, (float)w4.x, ax); ay = fmaf(v4, (float)w4.y, ay);
        ax = fmaf(v5, (float)w5.x, ax); ay = fmaf(v5, (float)w5.y, ay);
        ax = fmaf(v6, (float)w6.x, ax); ay = fmaf(v6, (float)w6.y, ay);
        ax = fmaf(v7, (float)w7.x, ax); ay = fmaf(v7, (float)w7.y, ay);
        ax = fmaf(v8, (float)w8.x, ax); ay = fmaf(v8, (float)w8.y, ay);
        ax = fmaf(v9, (float)w9.x, ax); ay = fmaf(v9, (float)w9.y, ay);
        ax = fmaf(va, (float)wa.x, ax); ay = fmaf(va, (float)wa.y, ay);
        ax = fmaf(vb, (float)wb.x, ax); ay = fmaf(vb, (float)wb.y, ay);
        ax = fmaf(vc, (float)wc.x, ax); ay = fmaf(vc, (float)wc.y, ay);
        ax = fmaf(vd, (float)wd.x, ax); ay = fmaf(vd, (float)wd.y, ay);
        ax = fmaf(ve, (float)we.x, ax); ay = fmaf(ve, (float)we.y, ay);
        ax = fmaf(vf, (float)wf.x, ax); ay = fmaf(vf, (float)wf.y, ay);
    }
    if (j + 8 <= end) {
        int4 p0 = *(const int4*)(packed + j);
        int4 p1 = *(const int4*)(packed + j + 2);
        int4 p2 = *(const int4*)(packed + j + 4);
        int4 p3 = *(const int4*)(packed + j + 6);
        half2_t w0 = h2[p0.x * 64 + lane];
        half2_t w1 = h2[p0.z * 64 + lane];
        half2_t w2 = h2[p1.x * 64 + lane];
        half2_t w3 = h2[p1.z * 64 + lane];
        half2_t w4 = h2[p2.x * 64 + lane];
        half2_t w5 = h2[p2.z * 64 + lane];
        half2_t w6 = h2[p3.x * 64 + lane];
        half2_t w7 = h2[p3.z * 64 + lane];
        float v0 = __int_as_float(p0.y), v1 = __int_as_float(p0.w);
        float v2 = __int_as_float(p1.y), v3 = __int_as_float(p1.w);
        float v4 = __int_as_float(p2.y), v5 = __int_as_float(p2.w);
        float v6 = __int_as_float(p3.y), v7 = __int_as_float(p3.w);
        ax = fmaf(v0, (float)w0.x, ax); ay = fmaf(v0, (float)w0.y, ay);
        ax = fmaf(v1, (float)w1.x, ax); ay = fmaf(v1, (float)w1.y, ay);
        ax = fmaf(v2, (float)w2.x, ax); ay = fmaf(v2, (float)w2.y, ay);
        ax = fmaf(v3, (float)w3.x, ax); ay = fmaf(v3, (float)w3.y, ay);
        ax = fmaf(v4, (float)w4.x, ax); ay = fmaf(v4, (float)w4.y, ay);
        ax = fmaf(v5, (float)w5.x, ax); ay = fmaf(v5, (float)w5.y, ay);
        ax = fmaf(v6, (float)w6.x, ax); ay = fmaf(v6, (float)w6.y, ay);
        ax = fmaf(v7, (float)w7.x, ax); ay = fmaf(v7, (float)w7.y, ay);
        j += 8;
    }
    if (j + 4 <= end) {
        int4 p0 = *(const int4*)(packed + j);
        int4 p1 = *(const int4*)(packed + j + 2);
        half2_t w0 = h2[p0.x * 64 + lane];
        half2_t w1 = h2[p0.z * 64 + lane];
        half2_t w2 = h2[p1.x * 64 + lane];
        half2_t w3 = h2[p1.z * 64 + lane];
        float v0 = __int_as_float(p0.y), v1 = __int_as_float(p0.w);
        float v2 = __int_as_float(p1.y), v3 = __int_as_float(p1.w);
        ax = fmaf(v0, (float)w0.x, ax); ay = fmaf(v0, (float)w0.y, ay);
        ax = fmaf(v1, (float)w1.x, ax); ay = fmaf(v1, (float)w1.y, ay);
        ax = fmaf(v2, (float)w2.x, ax); ay = fmaf(v2, (float)w2.y, ay);
        ax = fmaf(v3, (float)w3.x, ax); ay = fmaf(v3, (float)w3.y, ay);
        j += 4;
    }
    for (; j < end; ++j) {
        int2 e = packed[j];
        half2_t w = h2[e.x * 64 + lane];
        float v = __int_as_float(e.y);
        ax = fmaf(v, (float)w.x, ax); ay = fmaf(v, (float)w.y, ay);
    }
    out2[r * 64 + lane] = make_float2(fmaxf(ax, 0.0f), fmaxf(ay, 0.0f));
}

// ---------------------------------------------------------------------------
// Fallback atomic path (only if ws too small).
__global__ void spmm1_atomic_kernel(const float* __restrict__ xv,
                                    const int* __restrict__ xr,
                                    const int* __restrict__ xc,
                                    const void* __restrict__ mask,
                                    const float* __restrict__ kern,
                                    const int* __restrict__ flags,
                                    float* __restrict__ h, int nnz) {
    long long gid = (long long)blockIdx.x * blockDim.x + threadIdx.x;
    int e = (int)(gid >> 7);
    if (e >= nnz) return;
    int o = (int)(gid & 127);
    bool keep;
    if (flags[0] == 0)      keep = ((const int*)mask)[e] != 0;
    else if (flags[1] == 0) keep = ((const float*)mask)[e] != 0.0f;
    else                    keep = ((const unsigned char*)mask)[e] != 0;
    if (!keep) return;
    atomicAdd(&h[(long long)xr[e] * O_DIM + o], xv[e] * KEEP_INV * kern[xc[e] * O_DIM + o]);
}

__global__ void spmm2_atomic_kernel(const float* __restrict__ av,
                                    const int* __restrict__ ar,
                                    const int* __restrict__ ac,
                                    const float* __restrict__ h,
                                    float* __restrict__ out, int nnz) {
    long long gid = (long long)blockIdx.x * blockDim.x + threadIdx.x;
    int e = (int)(gid >> 7);
    if (e >= nnz) return;
    int o = (int)(gid & 127);
    atomicAdd(&out[(long long)ar[e] * O_DIM + o], av[e] * h[(long long)ac[e] * O_DIM + o]);
}

__global__ void relu_kernel(float* __restrict__ out, int n4) {
    int stride = gridDim.x * blockDim.x;
    float4* p = (float4*)out;
    for (int i = blockIdx.x * blockDim.x + threadIdx.x; i < n4; i += stride) {
        float4 v = p[i];
        v.x = fmaxf(v.x, 0.0f); v.y = fmaxf(v.y, 0.0f);
        v.z = fmaxf(v.z, 0.0f); v.w = fmaxf(v.w, 0.0f);
        p[i] = v;
    }
}

// ---------------------------------------------------------------------------
static inline size_t align256(size_t x) { return (x + 255) & ~(size_t)255; }

extern "C" void kernel_launch(void* const* d_in, const int* in_sizes, int n_in,
                              void* d_out, int out_size, void* d_ws, size_t ws_size,
                              hipStream_t stream) {
    const float* x_vals   = (const float*)d_in[0];
    const float* kern     = (const float*)d_in[1];   // [256 x 128]
    const float* adj_vals = (const float*)d_in[2];
    const int*   x_rows   = (const int*)d_in[3];
    const int*   x_cols   = (const int*)d_in[4];
    const int*   adj_rows = (const int*)d_in[5];
    const int*   adj_cols = (const int*)d_in[6];
    const void*  mask     = d_in[7];

    const int nnz_x = in_sizes[0];
    const int nnz_a = in_sizes[2];
    const int n_nodes = out_size / O_DIM;
    const int ntot = 2 * n_nodes;
    const int nbuck = (ntot + BUCK_BINS - 1) / BUCK_BINS;
    const long long nnz_tot = (long long)nnz_x + nnz_a;
    const int B = (int)((nnz_tot + TILE - 1) / TILE);           // tiles
    const long long n_scan = (long long)nbuck * B;              // KxB matrix
    const int nb_scan = (int)((n_scan + SCAN_CHUNK - 1) / SCAN_CHUNK);

    float* out = (float*)d_out;
    char* ws = (char*)d_ws;

    // ---- ws carve-up: fixed buffers first, then PAD-dependent rec/packed ----
    size_t off = 0;
    int* flags = (int*)d_ws;            off = align256(off + 2 * sizeof(int));
    size_t o_k16 = off;                 off = align256(off + 256 * 128 * sizeof(half_t));
    size_t o_histT = off;               off = align256(off + (size_t)n_scan * 4);
    size_t o_tofs = off;                off = align256(off + ((size_t)n_scan + 1) * 4);
    size_t o_bsums = off;               off = align256(off + 4096 * 4);
    size_t o_S = off;                   off = align256(off + ((size_t)ntot + 1) * 4);
    size_t o_E = off;                   off = align256(off + (size_t)ntot * 4);
    size_t o_h = off;                   off = align256(off + (size_t)n_nodes * O_DIM * sizeof(half_t));
    const size_t fixed_end = off;

    // choose largest PAD in {8,4,2,1} whose worst-case rec+packed fit ws
    int PAD = 8;
    long long rec_cap = 0;
    while (true) {
        rec_cap = nnz_tot + (long long)(PAD - 1) * n_scan;   // worst-case records
        size_t need = fixed_end + 2 * align256((size_t)rec_cap * 8);
        if (need <= ws_size || PAD == 1) break;
        PAD >>= 1;
    }
    size_t o_rec = fixed_end;
    size_t o_packed = o_rec + align256((size_t)rec_cap * 8);
    size_t total_need = o_packed + align256((size_t)rec_cap * 8);

    const bool csr_ok = (total_need <= ws_size) && (nbuck <= 1024) &&
                        (n_nodes < (1 << 17)) && (nb_scan <= 1024);

    // mask format detection (both paths need it)
    int scan_words = nnz_x / 4;
    if (scan_words > 16384) scan_words = 16384;
    detect_mask_kernel<<<1, 256, 0, stream>>>((const unsigned int*)mask, scan_words, flags);

    if (csr_ok) {
        half2_t* k16 = (half2_t*)(ws + o_k16);
        int*  histT  = (int*)(ws + o_histT);
        int*  tofs   = (int*)(ws + o_tofs);
        int*  bsums  = (int*)(ws + o_bsums);
        int*  S      = (int*)(ws + o_S);
        int*  E      = (int*)(ws + o_E);
        int2* rec    = (int2*)(ws + o_rec);
        int2* packed = (int2*)(ws + o_packed);
        half2_t* h2  = (half2_t*)(ws + o_h);

        // 0) kernel matrix -> f16 (16384 half2)
        conv_kern_kernel<<<64, 256, 0, stream>>>((const float2*)kern, k16, 16384);
        // A) per-tile bucket histograms (transposed, padded to PAD records)
        tile_hist_kernel<<<B, MS_THREADS, 0, stream>>>(x_rows, nnz_x, adj_rows, nnz_a,
                                                       n_nodes, nbuck, B, PAD, histT);
        // B) exclusive scan of the KxB matrix -> line-aligned chunk offsets
        scan_partial_kernel<<<nb_scan, SCAN_BS, 0, stream>>>(histT, (int)n_scan, bsums);
        scan_blocksums_kernel<<<1, 1024, 0, stream>>>(bsums, nb_scan, &tofs[n_scan]);
        scan_final_kernel<<<nb_scan, SCAN_BS, 0, stream>>>(histT, (int)n_scan, bsums, tofs);
        // C) multisplit: deterministic scatter + marked pad fill
        multisplit_kernel<<<B, MS_THREADS, 0, stream>>>(x_vals, x_rows, x_cols, mask, flags,
                                                        adj_vals, adj_rows, adj_cols,
                                                        nnz_x, nnz_a, n_nodes, nbuck, B,
                                                        tofs, rec);
        // D) per-bucket counting sort (drops pads) -> packed + exact [S,E)
        bucket_sort_kernel<<<nbuck, 256, 0, stream>>>(rec, tofs, B, ntot, packed, S, E);
        // E) SpMM1 (f16 weight gathers): h = dropout(X) @ kernel
        {
            int blocks = (n_nodes * 64 + 255) / 256;
            spmm1_wave_kernel<<<blocks, 256, 0, stream>>>(S, E, packed, k16, h2, n_nodes);
        }
        // F) SpMM2 + ReLU: out = relu(adj @ h)
        {
            int blocks = (n_nodes * 64 + 255) / 256;
            spmm2_wave_kernel<<<blocks, 256, 0, stream>>>(S + n_nodes, E + n_nodes,
                                                          packed, h2, (float2*)out, n_nodes);
        }
    } else {
        // ---- fallback: atomic path ----
        float* h = (float*)(ws + 256);
        hipMemsetAsync(h, 0, (size_t)n_nodes * O_DIM * 4, stream);
        hipMemsetAsync(out, 0, (size_t)out_size * 4, stream);
        {
            long long threads = (long long)nnz_x * O_DIM;
            int blocks = (int)((threads + 255) / 256);
            spmm1_atomic_kernel<<<blocks, 256, 0, stream>>>(x_vals, x_rows, x_cols, mask,
                                                            kern, flags, h, nnz_x);
            threads = (long long)nnz_a * O_DIM;
            blocks = (int)((threads + 255) / 256);
            spmm2_atomic_kernel<<<blocks, 256, 0, stream>>>(adj_vals, adj_rows, adj_cols,
                                                            h, out, nnz_a);
        }
        int n4 = out_size / 4;
        int blocks = (n4 + 255) / 256; if (blocks > 2048) blocks = 2048;
        relu_kernel<<<blocks, 256, 0, stream>>>(out, n4);
    }
}

// Round 12
// 212.513 us; speedup vs baseline: 1.4662x; 1.1014x over previous
//
#include <hip/hip_runtime.h>
#include <hip/hip_bf16.h>

// GraphSparseConvolution on MI355X.
// Round 12: mid-tier tune. TILE 8192 w/ 1024-thread build blocks (same
// ~24 waves/CU, half the chunks -> pad inflation 67%->33%, half the scan);
// bucket_sort 512 threads (12->24 waves/CU); conv_kern fused into the
// detect/init kernel. spmm2 (66us) is at its random-gather roofline
// (410MB logical at ~6.2 TB/s effective) and is unchanged.
// Fallback to atomic path if ws too small.

static constexpr int O_DIM = 128;
static constexpr float KEEP_INV = 1.0f / 0.9f;  // 1/keep_prob
static constexpr int BUCK_BINS = 256;           // rows per coarse bucket
static constexpr int TILE = 8192;               // edges per multisplit tile
static constexpr int MS_THREADS = 1024;         // threads per build block
static constexpr int MS_ITER = TILE / MS_THREADS;   // 8
static constexpr unsigned PAD_COL = 0x1FFFFu;   // reserved pad marker column

using half_t = _Float16;
using half2_t = _Float16 __attribute__((ext_vector_type(2)));

// ---------------------------------------------------------------------------
// Block 0: detect how the harness materialized the bool keep_mask
// (int32/f32/uint8). Blocks 1..64: convert kernel matrix f32 -> f16.
__global__ void init_kernel(const unsigned int* __restrict__ w, int nwords,
                            int* __restrict__ flags,
                            const float2* __restrict__ kern2,
                            half2_t* __restrict__ k16) {
    int t = threadIdx.x;
    if (blockIdx.x == 0) {
        __shared__ int sA[256];
        __shared__ int sB[256];
        int violA = 0, violB = 0;
        for (int i = t; i < nwords; i += 256) {
            unsigned int x = w[i];
            violA |= (x > 1u) ? 1 : 0;
            violB |= (x != 0u && x != 0x3F800000u) ? 1 : 0;
        }
        sA[t] = violA; sB[t] = violB;
        __syncthreads();
        for (int s = 128; s > 0; s >>= 1) {
            if (t < s) { sA[t] |= sA[t + s]; sB[t] |= sB[t + s]; }
            __syncthreads();
        }
        if (t == 0) { flags[0] = sA[0]; flags[1] = sB[0]; }
    } else {
        int i = (blockIdx.x - 1) * 256 + t;   // 64 blocks x 256 = 16384
        float2 v = kern2[i];
        half2_t o; o.x = (half_t)v.x; o.y = (half_t)v.y;
        k16[i] = o;
    }
}

// ---------------------------------------------------------------------------
// A) per-tile bucket histogram, PADDED to `pad` records per chunk, written
// transposed: histT[k*B + b]. 1024 threads, batched loads.
__global__ __launch_bounds__(MS_THREADS) void tile_hist_kernel(
        const int* __restrict__ xr, int nnz_x,
        const int* __restrict__ ar, int nnz_a,
        int n_nodes, int nbuck, int B, int pad,
        int* __restrict__ histT) {
    __shared__ int hist[1024];
    int b = blockIdx.x, t = threadIdx.x;
    for (int k = t; k < 1024; k += MS_THREADS) hist[k] = 0;
    __syncthreads();
    int tot = nnz_x + nnz_a;
    int tstart = b * TILE;
    int tend = min(tstart + TILE, tot);
    int bin[MS_ITER];
    #pragma unroll
    for (int u = 0; u < MS_ITER; ++u) {
        int i = tstart + t + u * MS_THREADS;
        bin[u] = (i < tend) ? ((i < nnz_x) ? xr[i] : (n_nodes + ar[i - nnz_x])) : -1;
    }
    #pragma unroll
    for (int u = 0; u < MS_ITER; ++u)
        if (bin[u] >= 0) atomicAdd(&hist[bin[u] >> 8], 1);
    __syncthreads();
    int pm = pad - 1;
    for (int k = t; k < nbuck; k += MS_THREADS)
        histT[(size_t)k * B + b] = (hist[k] + pm) & ~pm;
}

// ---------------------------------------------------------------------------
// 3-phase exclusive scan over cnt[0..n) -> S[0..n).
static constexpr int SCAN_BS = 256;
static constexpr int SCAN_IPT = 8;
static constexpr int SCAN_CHUNK = SCAN_BS * SCAN_IPT;  // 2048

__global__ __launch_bounds__(SCAN_BS) void scan_partial_kernel(const int* __restrict__ cnt,
                                                               int n, int* __restrict__ bsums) {
    int b = blockIdx.x, t = threadIdx.x;
    int lane = t & 63, wid = t >> 6;
    __shared__ int wsum[SCAN_BS / 64];
    int base = b * SCAN_CHUNK + t * SCAN_IPT;
    int s = 0;
    #pragma unroll
    for (int k = 0; k < SCAN_IPT; ++k) {
        int i = base + k;
        s += (i < n) ? cnt[i] : 0;
    }
    #pragma unroll
    for (int d = 1; d < 64; d <<= 1) s += __shfl_xor(s, d, 64);
    if (lane == 0) wsum[wid] = s;
    __syncthreads();
    if (t == 0) {
        int tot = 0;
        #pragma unroll
        for (int w = 0; w < SCAN_BS / 64; ++w) tot += wsum[w];
        bsums[b] = tot;
    }
}

__global__ __launch_bounds__(1024) void scan_blocksums_kernel(int* __restrict__ bsums, int nb,
                                                              int* __restrict__ sent0) {
    __shared__ int wsum[16];
    int t = threadIdx.x, lane = t & 63, wid = t >> 6;
    int v = (t < nb) ? bsums[t] : 0;
    int s = v;
    #pragma unroll
    for (int d = 1; d < 64; d <<= 1) {
        int u = __shfl_up(s, d, 64);
        if (lane >= d) s += u;
    }
    if (lane == 63) wsum[wid] = s;
    __syncthreads();
    int woff = 0;
    for (int w = 0; w < wid; ++w) woff += wsum[w];
    if (t < nb) bsums[t] = woff + s - v;      // exclusive
    if (t == 1023) *sent0 = woff + s;         // padded grand total
}

__global__ __launch_bounds__(SCAN_BS) void scan_final_kernel(const int* __restrict__ cnt, int n,
                                                             const int* __restrict__ bsums,
                                                             int* __restrict__ S) {
    __shared__ int wsum[SCAN_BS / 64];
    int b = blockIdx.x, t = threadIdx.x;
    int lane = t & 63, wid = t >> 6;
    int base = b * SCAN_CHUNK + t * SCAN_IPT;
    int v[SCAN_IPT];
    int tsum = 0;
    #pragma unroll
    for (int k = 0; k < SCAN_IPT; ++k) {
        int i = base + k;
        v[k] = (i < n) ? cnt[i] : 0;
        tsum += v[k];
    }
    int s = tsum;
    #pragma unroll
    for (int d = 1; d < 64; d <<= 1) {
        int u = __shfl_up(s, d, 64);
        if (lane >= d) s += u;
    }
    if (lane == 63) wsum[wid] = s;
    __syncthreads();
    int woff = 0;
    for (int w = 0; w < wid; ++w) woff += wsum[w];
    int excl = bsums[b] + woff + (s - tsum);
    #pragma unroll
    for (int k = 0; k < SCAN_IPT; ++k) {
        int i = base + k;
        if (i < n) S[i] = excl;
        excl += v[k];
    }
}

// ---------------------------------------------------------------------------
// C) multisplit: deterministic placement via LDS cursors seeded from tofs.
// 1024 threads; all MS_ITER iterations' inputs preloaded into registers,
// then the atomic+store chain runs. Pad-fill with marked records at the end
// (line-exclusive writes; pads dropped by bucket_sort).
__global__ __launch_bounds__(MS_THREADS) void multisplit_kernel(
        const float* __restrict__ xv,
        const int* __restrict__ xr,
        const int* __restrict__ xc,
        const void* __restrict__ mask,
        const int* __restrict__ flags,
        const float* __restrict__ av,
        const int* __restrict__ ar,
        const int* __restrict__ ac,
        int nnz_x, int nnz_a, int n_nodes,
        int nbuck, int B,
        const int* __restrict__ tofs,
        int2* __restrict__ rec) {
    __shared__ int cur[1024];
    int b = blockIdx.x, t = threadIdx.x;
    for (int k = t; k < nbuck; k += MS_THREADS)
        cur[k] = tofs[(size_t)k * B + b];
    __syncthreads();
    int tot = nnz_x + nnz_a;
    int tstart = b * TILE;
    int tend = min(tstart + TILE, tot);
    int f0 = flags[0], f1 = flags[1];

    int bin[MS_ITER], col[MS_ITER];
    float val[MS_ITER];
    #pragma unroll
    for (int u = 0; u < MS_ITER; ++u) {
        int i = tstart + t + u * MS_THREADS;
        bin[u] = -1;
        if (i < tend) {
            if (i < nnz_x) {
                bin[u] = xr[i];
                col[u] = xc[i];
                bool keep;
                if (f0 == 0)      keep = ((const int*)mask)[i] != 0;
                else if (f1 == 0) keep = ((const float*)mask)[i] != 0.0f;
                else              keep = ((const unsigned char*)mask)[i] != 0;
                val[u] = keep ? xv[i] * KEEP_INV : 0.0f;
            } else {
                int e = i - nnz_x;
                bin[u] = n_nodes + ar[e];
                col[u] = ac[e];
                val[u] = av[e];
            }
        }
    }
    #pragma unroll
    for (int u = 0; u < MS_ITER; ++u) {
        if (bin[u] >= 0) {
            int key = ((bin[u] & (BUCK_BINS - 1)) << 17) | col[u];
            int pos = atomicAdd(&cur[bin[u] >> 8], 1);   // LDS atomic — cheap
            rec[pos] = make_int2(key, __float_as_int(val[u]));
        }
    }
    __syncthreads();
    // pad-fill with marked records (col = PAD_COL -> dropped in bucket_sort)
    int fillkey = (int)((((unsigned)b & (BUCK_BINS - 1)) << 17) | PAD_COL);
    for (int k = t; k < nbuck; k += MS_THREADS) {
        int fl = k * B + b;
        int pe = tofs[fl + 1];
        for (int p = cur[k]; p < pe; ++p)
            rec[p] = make_int2(fillkey, 0);
    }
}

// ---------------------------------------------------------------------------
// D) per-bucket LDS counting sort over REAL records -> packed + exact
// per-row [S, E) bounds. 512 threads: streaming passes use all 8 waves,
// the 256-bin scan phase uses the first 4 waves.
__global__ __launch_bounds__(512) void bucket_sort_kernel(
        const int2* __restrict__ rec,
        const int* __restrict__ tofs, int B,
        int ntot, int2* __restrict__ packed,
        int* __restrict__ S, int* __restrict__ E) {
    __shared__ int hist[256];
    __shared__ int cur[256];
    __shared__ int wsum[4];
    int bb = blockIdx.x, t = threadIdx.x;
    int start = tofs[(size_t)bb * B];
    int end   = tofs[(size_t)(bb + 1) * B];
    if (t < 256) hist[t] = 0;
    __syncthreads();
    for (int i = start + t; i < end; i += 512) {
        unsigned k = (unsigned)rec[i].x;
        if ((k & PAD_COL) != PAD_COL)
            atomicAdd(&hist[k >> 17], 1);
    }
    __syncthreads();
    int v = 0, s = 0;
    int lane = t & 63, wid = t >> 6;
    if (t < 256) {                       // waves 0..3 scan the 256 bins
        v = hist[t];
        s = v;
        #pragma unroll
        for (int d = 1; d < 64; d <<= 1) {
            int u = __shfl_up(s, d, 64);
            if (lane >= d) s += u;
        }
        if (lane == 63) wsum[wid] = s;
    }
    __syncthreads();
    if (t < 256) {
        int woff = 0;
        for (int w = 0; w < wid; ++w) woff += wsum[w];
        int excl = woff + s - v;
        int binBase = bb << 8;
        if (binBase + t < ntot) {
            S[binBase + t] = start + excl;
            E[binBase + t] = start + excl + v;
        }
        cur[t] = start + excl;
    }
    __syncthreads();
    for (int i = start + t; i < end; i += 512) {
        int2 e = rec[i];
        unsigned k = (unsigned)e.x;
        if ((k & PAD_COL) == PAD_COL) continue;   // drop pads
        int pos = atomicAdd(&cur[k >> 17], 1);
        packed[pos] = make_int2((int)(k & PAD_COL), e.y);
    }
}

// ---------------------------------------------------------------------------
// E) SpMM1: wave-per-row, f16 weight gathers, int4 edge loads, 8-deep
// pipeline with 4-deep + scalar tails. src = k16 (half2), dst = h (f16x2).
__global__ __launch_bounds__(256) void spmm1_wave_kernel(
        const int* __restrict__ S, const int* __restrict__ E,
        const int2* __restrict__ packed,
        const half2_t* __restrict__ k16, half2_t* __restrict__ h2,
        int n_rows) {
    int gid = blockIdx.x * 256 + threadIdx.x;
    int r = gid >> 6;
    if (r >= n_rows) return;
    int lane = gid & 63;
    int j = S[r], end = E[r];
    float ax = 0.0f, ay = 0.0f;
    if ((j & 1) && j < end) {   // peel to 16B-align packed reads
        int2 e = packed[j];
        half2_t w = k16[e.x * 64 + lane];
        float v = __int_as_float(e.y);
        ax = fmaf(v, (float)w.x, ax); ay = fmaf(v, (float)w.y, ay);
        ++j;
    }
    for (; j + 8 <= end; j += 8) {
        int4 p0 = *(const int4*)(packed + j);
        int4 p1 = *(const int4*)(packed + j + 2);
        int4 p2 = *(const int4*)(packed + j + 4);
        int4 p3 = *(const int4*)(packed + j + 6);
        half2_t w0 = k16[p0.x * 64 + lane];
        half2_t w1 = k16[p0.z * 64 + lane];
        half2_t w2 = k16[p1.x * 64 + lane];
        half2_t w3 = k16[p1.z * 64 + lane];
        half2_t w4 = k16[p2.x * 64 + lane];
        half2_t w5 = k16[p2.z * 64 + lane];
        half2_t w6 = k16[p3.x * 64 + lane];
        half2_t w7 = k16[p3.z * 64 + lane];
        float v0 = __int_as_float(p0.y), v1 = __int_as_float(p0.w);
        float v2 = __int_as_float(p1.y), v3 = __int_as_float(p1.w);
        float v4 = __int_as_float(p2.y), v5 = __int_as_float(p2.w);
        float v6 = __int_as_float(p3.y), v7 = __int_as_float(p3.w);
        ax = fmaf(v0, (float)w0.x, ax); ay = fmaf(v0, (float)w0.y, ay);
        ax = fmaf(v1, (float)w1.x, ax); ay = fmaf(v1, (float)w1.y, ay);
        ax = fmaf(v2, (float)w2.x, ax); ay = fmaf(v2, (float)w2.y, ay);
        ax = fmaf(v3, (float)w3.x, ax); ay = fmaf(v3, (float)w3.y, ay);
        ax = fmaf(v4, (float)w4.x, ax); ay = fmaf(v4, (float)w4.y, ay);
        ax = fmaf(v5, (float)w5.x, ax); ay = fmaf(v5, (float)w5.y, ay);
        ax = fmaf(v6, (float)w6.x, ax); ay = fmaf(v6, (float)w6.y, ay);
        ax = fmaf(v7, (float)w7.x, ax); ay = fmaf(v7, (float)w7.y, ay);
    }
    if (j + 4 <= end) {
        int4 p0 = *(const int4*)(packed + j);
        int4 p1 = *(const int4*)(packed + j + 2);
        half2_t w0 = k16[p0.x * 64 + lane];
        half2_t w1 = k16[p0.z * 64 + lane];
        half2_t w2 = k16[p1.x * 64 + lane];
        half2_t w3 = k16[p1.z * 64 + lane];
        float v0 = __int_as_float(p0.y), v1 = __int_as_float(p0.w);
        float v2 = __int_as_float(p1.y), v3 = __int_as_float(p1.w);
        ax = fmaf(v0, (float)w0.x, ax); ay = fmaf(v0, (float)w0.y, ay);
        ax = fmaf(v1, (float)w1.x, ax); ay = fmaf(v1, (float)w1.y, ay);
        ax = fmaf(v2, (float)w2.x, ax); ay = fmaf(v2, (float)w2.y, ay);
        ax = fmaf(v3, (float)w3.x, ax); ay = fmaf(v3, (float)w3.y, ay);
        j += 4;
    }
    for (; j < end; ++j) {
        int2 e = packed[j];
        half2_t w = k16[e.x * 64 + lane];
        float v = __int_as_float(e.y);
        ax = fmaf(v, (float)w.x, ax); ay = fmaf(v, (float)w.y, ay);
    }
    half2_t o; o.x = (half_t)ax; o.y = (half_t)ay;
    h2[r * 64 + lane] = o;
}

// ---------------------------------------------------------------------------
// F) SpMM2 + ReLU: wave-per-row, 16-deep gather pipeline with 8/4/scalar
// tails, int4 edge loads. At the random-gather roofline (~6.2 TB/s logical).
__global__ __launch_bounds__(256) void spmm2_wave_kernel(
        const int* __restrict__ S, const int* __restrict__ E,
        const int2* __restrict__ packed,
        const half2_t* __restrict__ h2, float2* __restrict__ out2,
        int n_rows) {
    int gid = blockIdx.x * 256 + threadIdx.x;
    int r = gid >> 6;
    if (r >= n_rows) return;
    int lane = gid & 63;
    int j = S[r], end = E[r];
    float ax = 0.0f, ay = 0.0f;
    if ((j & 1) && j < end) {
        int2 e = packed[j];
        half2_t w = h2[e.x * 64 + lane];
        float v = __int_as_float(e.y);
        ax = fmaf(v, (float)w.x, ax); ay = fmaf(v, (float)w.y, ay);
        ++j;
    }
    for (; j + 16 <= end; j += 16) {
        int4 p0 = *(const int4*)(packed + j);
        int4 p1 = *(const int4*)(packed + j + 2);
        int4 p2 = *(const int4*)(packed + j + 4);
        int4 p3 = *(const int4*)(packed + j + 6);
        int4 p4 = *(const int4*)(packed + j + 8);
        int4 p5 = *(const int4*)(packed + j + 10);
        int4 p6 = *(const int4*)(packed + j + 12);
        int4 p7 = *(const int4*)(packed + j + 14);
        half2_t w0 = h2[p0.x * 64 + lane];
        half2_t w1 = h2[p0.z * 64 + lane];
        half2_t w2 = h2[p1.x * 64 + lane];
        half2_t w3 = h2[p1.z * 64 + lane];
        half2_t w4 = h2[p2.x * 64 + lane];
        half2_t w5 = h2[p2.z * 64 + lane];
        half2_t w6 = h2[p3.x * 64 + lane];
        half2_t w7 = h2[p3.z * 64 + lane];
        half2_t w8 = h2[p4.x * 64 + lane];
        half2_t w9 = h2[p4.z * 64 + lane];
        half2_t wa = h2[p5.x * 64 + lane];
        half2_t wb = h2[p5.z * 64 + lane];
        half2_t wc = h2[p6.x * 64 + lane];
        half2_t wd = h2[p6.z * 64 + lane];
        half2_t we = h2[p7.x * 64 + lane];
        half2_t wf = h2[p7.z * 64 + lane];
        float v0 = __int_as_float(p0.y), v1 = __int_as_float(p0.w);
        float v2 = __int_as_float(p1.y), v3 = __int_as_float(p1.w);
        float v4 = __int_as_float(p2.y), v5 = __int_as_float(p2.w);
        float v6 = __int_as_float(p3.y), v7 = __int_as_float(p3.w);
        float v8 = __int_as_float(p4.y), v9 = __int_as_float(p4.w);
        float va = __int_as_float(p5.y), vb = __int_as_float(p5.w);
        float vc = __int_as_float(p6.y), vd = __int_as_float(p6.w);
        float ve = __int_as_float(p7.y), vf = __int_as_float(p7.w);
        ax = fmaf(v0, (float)w0.x, ax); ay = fmaf(v0, (float)w0.y, ay);
        ax = fmaf(v1, (float)w1.x, ax); ay = fmaf(v1, (float)w1.y, ay);
        ax = fmaf(v2, (float)w2.x, ax); ay = fmaf(v2, (float)w2.y, ay);
        ax = fmaf(v3, (float)w3.x, ax); ay = fmaf(v3, (float)w3.y, ay);
        ax = fmaf(v4, (float)w4.x, ax); ay = fmaf(v4, (float)w4.y, ay);
        ax = fmaf(v5, (float)w5.x, ax); ay = fmaf(v5, (float)w5.y, ay);
        ax = fmaf(v6, (float)w6.x, ax); ay = fmaf(v6, (float)w6.y, ay);
        ax = fmaf(v7, (float)w7.x, ax); ay = fmaf(v7, (float)w7.y, ay);
        ax = fmaf(v8, (float)w8.x, ax); ay = fmaf(v8, (float)w8.y, ay);
        ax = fmaf(v9, (float)w9.x, ax); ay = fmaf(v9, (float)w9.y, ay);
        ax = fmaf(va, (float)wa.x, ax); ay = fmaf(va, (float)wa.y, ay);
        ax = fmaf(vb, (float)wb.x, ax); ay = fmaf(vb, (float)wb.y, ay);
        ax = fmaf(vc, (float)wc.x, ax); ay = fmaf(vc, (float)wc.y, ay);
        ax = fmaf(vd, (float)wd.x, ax); ay = fmaf(vd, (float)wd.y, ay);
        ax = fmaf(ve, (float)we.x, ax); ay = fmaf(ve, (float)we.y, ay);
        ax = fmaf(vf, (float)wf.x, ax); ay = fmaf(vf, (float)wf.y, ay);
    }
    if (j + 8 <= end) {
        int4 p0 = *(const int4*)(packed + j);
        int4 p1 = *(const int4*)(packed + j + 2);
        int4 p2 = *(const int4*)(packed + j + 4);
        int4 p3 = *(const int4*)(packed + j + 6);
        half2_t w0 = h2[p0.x * 64 + lane];
        half2_t w1 = h2[p0.z * 64 + lane];
        half2_t w2 = h2[p1.x * 64 + lane];
        half2_t w3 = h2[p1.z * 64 + lane];
        half2_t w4 = h2[p2.x * 64 + lane];
        half2_t w5 = h2[p2.z * 64 + lane];
        half2_t w6 = h2[p3.x * 64 + lane];
        half2_t w7 = h2[p3.z * 64 + lane];
        float v0 = __int_as_float(p0.y), v1 = __int_as_float(p0.w);
        float v2 = __int_as_float(p1.y), v3 = __int_as_float(p1.w);
        float v4 = __int_as_float(p2.y), v5 = __int_as_float(p2.w);
        float v6 = __int_as_float(p3.y), v7 = __int_as_float(p3.w);
        ax = fmaf(v0, (float)w0.x, ax); ay = fmaf(v0, (float)w0.y, ay);
        ax = fmaf(v1, (float)w1.x, ax); ay = fmaf(v1, (float)w1.y, ay);
        ax = fmaf(v2, (float)w2.x, ax); ay = fmaf(v2, (float)w2.y, ay);
        ax = fmaf(v3, (float)w3.x, ax); ay = fmaf(v3, (float)w3.y, ay);
        ax = fmaf(v4, (float)w4.x, ax); ay = fmaf(v4, (float)w4.y, ay);
        ax = fmaf(v5, (float)w5.x, ax); ay = fmaf(v5, (float)w5.y, ay);
        ax = fmaf(v6, (float)w6.x, ax); ay = fmaf(v6, (float)w6.y, ay);
        ax = fmaf(v7, (float)w7.x, ax); ay = fmaf(v7, (float)w7.y, ay);
        j += 8;
    }
    if (j + 4 <= end) {
        int4 p0 = *(const int4*)(packed + j);
        int4 p1 = *(const int4*)(packed + j + 2);
        half2_t w0 = h2[p0.x * 64 + lane];
        half2_t w1 = h2[p0.z * 64 + lane];
        half2_t w2 = h2[p1.x * 64 + lane];
        half2_t w3 = h2[p1.z * 64 + lane];
        float v0 = __int_as_float(p0.y), v1 = __int_as_float(p0.w);
        float v2 = __int_as_float(p1.y), v3 = __int_as_float(p1.w);
        ax = fmaf(v0, (float)w0.x, ax); ay = fmaf(v0, (float)w0.y, ay);
        ax = fmaf(v1, (float)w1.x, ax); ay = fmaf(v1, (float)w1.y, ay);
        ax = fmaf(v2, (float)w2.x, ax); ay = fmaf(v2, (float)w2.y, ay);
        ax = fmaf(v3, (float)w3.x, ax); ay = fmaf(v3, (float)w3.y, ay);
        j += 4;
    }
    for (; j < end; ++j) {
        int2 e = packed[j];
        half2_t w = h2[e.x * 64 + lane];
        float v = __int_as_float(e.y);
        ax = fmaf(v, (float)w.x, ax); ay = fmaf(v, (float)w.y, ay);
    }
    out2[r * 64 + lane] = make_float2(fmaxf(ax, 0.0f), fmaxf(ay, 0.0f));
}

// ---------------------------------------------------------------------------
// Fallback atomic path (only if ws too small).
__global__ void fb_detect_mask_kernel(const unsigned int* __restrict__ w, int nwords,
                                      int* __restrict__ flags) {
    __shared__ int sA[256];
    __shared__ int sB[256];
    int t = threadIdx.x;
    int violA = 0, violB = 0;
    for (int i = t; i < nwords; i += 256) {
        unsigned int x = w[i];
        violA |= (x > 1u) ? 1 : 0;
        violB |= (x != 0u && x != 0x3F800000u) ? 1 : 0;
    }
    sA[t] = violA; sB[t] = violB;
    __syncthreads();
    for (int s = 128; s > 0; s >>= 1) {
        if (t < s) { sA[t] |= sA[t + s]; sB[t] |= sB[t + s]; }
        __syncthreads();
    }
    if (t == 0) { flags[0] = sA[0]; flags[1] = sB[0]; }
}

__global__ void spmm1_atomic_kernel(const float* __restrict__ xv,
                                    const int* __restrict__ xr,
                                    const int* __restrict__ xc,
                                    const void* __restrict__ mask,
                                    const float* __restrict__ kern,
                                    const int* __restrict__ flags,
                                    float* __restrict__ h, int nnz) {
    long long gid = (long long)blockIdx.x * blockDim.x + threadIdx.x;
    int e = (int)(gid >> 7);
    if (e >= nnz) return;
    int o = (int)(gid & 127);
    bool keep;
    if (flags[0] == 0)      keep = ((const int*)mask)[e] != 0;
    else if (flags[1] == 0) keep = ((const float*)mask)[e] != 0.0f;
    else                    keep = ((const unsigned char*)mask)[e] != 0;
    if (!keep) return;
    atomicAdd(&h[(long long)xr[e] * O_DIM + o], xv[e] * KEEP_INV * kern[xc[e] * O_DIM + o]);
}

__global__ void spmm2_atomic_kernel(const float* __restrict__ av,
                                    const int* __restrict__ ar,
                                    const int* __restrict__ ac,
                                    const float* __restrict__ h,
                                    float* __restrict__ out, int nnz) {
    long long gid = (long long)blockIdx.x * blockDim.x + threadIdx.x;
    int e = (int)(gid >> 7);
    if (e >= nnz) return;
    int o = (int)(gid & 127);
    atomicAdd(&out[(long long)ar[e] * O_DIM + o], av[e] * h[(long long)ac[e] * O_DIM + o]);
}

__global__ void relu_kernel(float* __restrict__ out, int n4) {
    int stride = gridDim.x * blockDim.x;
    float4* p = (float4*)out;
    for (int i = blockIdx.x * blockDim.x + threadIdx.x; i < n4; i += stride) {
        float4 v = p[i];
        v.x = fmaxf(v.x, 0.0f); v.y = fmaxf(v.y, 0.0f);
        v.z = fmaxf(v.z, 0.0f); v.w = fmaxf(v.w, 0.0f);
        p[i] = v;
    }
}

// ---------------------------------------------------------------------------
static inline size_t align256(size_t x) { return (x + 255) & ~(size_t)255; }

extern "C" void kernel_launch(void* const* d_in, const int* in_sizes, int n_in,
                              void* d_out, int out_size, void* d_ws, size_t ws_size,
                              hipStream_t stream) {
    const float* x_vals   = (const float*)d_in[0];
    const float* kern     = (const float*)d_in[1];   // [256 x 128]
    const float* adj_vals = (const float*)d_in[2];
    const int*   x_rows   = (const int*)d_in[3];
    const int*   x_cols   = (const int*)d_in[4];
    const int*   adj_rows = (const int*)d_in[5];
    const int*   adj_cols = (const int*)d_in[6];
    const void*  mask     = d_in[7];

    const int nnz_x = in_sizes[0];
    const int nnz_a = in_sizes[2];
    const int n_nodes = out_size / O_DIM;
    const int ntot = 2 * n_nodes;
    const int nbuck = (ntot + BUCK_BINS - 1) / BUCK_BINS;
    const long long nnz_tot = (long long)nnz_x + nnz_a;
    const int B = (int)((nnz_tot + TILE - 1) / TILE);           // tiles
    const long long n_scan = (long long)nbuck * B;              // KxB matrix
    const int nb_scan = (int)((n_scan + SCAN_CHUNK - 1) / SCAN_CHUNK);

    float* out = (float*)d_out;
    char* ws = (char*)d_ws;

    // ---- ws carve-up: fixed buffers first, then PAD-dependent rec/packed ----
    size_t off = 0;
    int* flags = (int*)d_ws;            off = align256(off + 2 * sizeof(int));
    size_t o_k16 = off;                 off = align256(off + 256 * 128 * sizeof(half_t));
    size_t o_histT = off;               off = align256(off + (size_t)n_scan * 4);
    size_t o_tofs = off;                off = align256(off + ((size_t)n_scan + 1) * 4);
    size_t o_bsums = off;               off = align256(off + 4096 * 4);
    size_t o_S = off;                   off = align256(off + ((size_t)ntot + 1) * 4);
    size_t o_E = off;                   off = align256(off + (size_t)ntot * 4);
    size_t o_h = off;                   off = align256(off + (size_t)n_nodes * O_DIM * sizeof(half_t));
    const size_t fixed_end = off;

    // choose largest PAD in {8,4,2,1} whose worst-case rec+packed fit ws
    int PAD = 8;
    long long rec_cap = 0;
    while (true) {
        rec_cap = nnz_tot + (long long)(PAD - 1) * n_scan;   // worst-case records
        size_t need = fixed_end + 2 * align256((size_t)rec_cap * 8);
        if (need <= ws_size || PAD == 1) break;
        PAD >>= 1;
    }
    size_t o_rec = fixed_end;
    size_t o_packed = o_rec + align256((size_t)rec_cap * 8);
    size_t total_need = o_packed + align256((size_t)rec_cap * 8);

    const bool csr_ok = (total_need <= ws_size) && (nbuck <= 1024) &&
                        (n_nodes < (1 << 17)) && (nb_scan <= 1024);

    int scan_words = nnz_x / 4;
    if (scan_words > 16384) scan_words = 16384;

    if (csr_ok) {
        half2_t* k16 = (half2_t*)(ws + o_k16);
        int*  histT  = (int*)(ws + o_histT);
        int*  tofs   = (int*)(ws + o_tofs);
        int*  bsums  = (int*)(ws + o_bsums);
        int*  S      = (int*)(ws + o_S);
        int*  E      = (int*)(ws + o_E);
        int2* rec    = (int2*)(ws + o_rec);
        int2* packed = (int2*)(ws + o_packed);
        half2_t* h2  = (half2_t*)(ws + o_h);

        // 0) mask detect + kernel f32->f16 (fused: block 0 / blocks 1..64)
        init_kernel<<<65, 256, 0, stream>>>((const unsigned int*)mask, scan_words,
                                            flags, (const float2*)kern, k16);
        // A) per-tile bucket histograms (transposed, padded to PAD records)
        tile_hist_kernel<<<B, MS_THREADS, 0, stream>>>(x_rows, nnz_x, adj_rows, nnz_a,
                                                       n_nodes, nbuck, B, PAD, histT);
        // B) exclusive scan of the KxB matrix -> line-aligned chunk offsets
        scan_partial_kernel<<<nb_scan, SCAN_BS, 0, stream>>>(histT, (int)n_scan, bsums);
        scan_blocksums_kernel<<<1, 1024, 0, stream>>>(bsums, nb_scan, &tofs[n_scan]);
        scan_final_kernel<<<nb_scan, SCAN_BS, 0, stream>>>(histT, (int)n_scan, bsums, tofs);
        // C) multisplit: deterministic scatter + marked pad fill
        multisplit_kernel<<<B, MS_THREADS, 0, stream>>>(x_vals, x_rows, x_cols, mask, flags,
                                                        adj_vals, adj_rows, adj_cols,
                                                        nnz_x, nnz_a, n_nodes, nbuck, B,
                                                        tofs, rec);
        // D) per-bucket counting sort (drops pads) -> packed + exact [S,E)
        bucket_sort_kernel<<<nbuck, 512, 0, stream>>>(rec, tofs, B, ntot, packed, S, E);
        // E) SpMM1 (f16 weight gathers): h = dropout(X) @ kernel
        {
            int blocks = (n_nodes * 64 + 255) / 256;
            spmm1_wave_kernel<<<blocks, 256, 0, stream>>>(S, E, packed, k16, h2, n_nodes);
        }
        // F) SpMM2 + ReLU: out = relu(adj @ h)
        {
            int blocks = (n_nodes * 64 + 255) / 256;
            spmm2_wave_kernel<<<blocks, 256, 0, stream>>>(S + n_nodes, E + n_nodes,
                                                          packed, h2, (float2*)out, n_nodes);
        }
    } else {
        // ---- fallback: atomic path ----
        fb_detect_mask_kernel<<<1, 256, 0, stream>>>((const unsigned int*)mask,
                                                     scan_words, flags);
        float* h = (float*)(ws + 256);
        hipMemsetAsync(h, 0, (size_t)n_nodes * O_DIM * 4, stream);
        hipMemsetAsync(out, 0, (size_t)out_size * 4, stream);
        {
            long long threads = (long long)nnz_x * O_DIM;
            int blocks = (int)((threads + 255) / 256);
            spmm1_atomic_kernel<<<blocks, 256, 0, stream>>>(x_vals, x_rows, x_cols, mask,
                                                            kern, flags, h, nnz_x);
            threads = (long long)nnz_a * O_DIM;
            blocks = (int)((threads + 255) / 256);
            spmm2_atomic_kernel<<<blocks, 256, 0, stream>>>(adj_vals, adj_rows, adj_cols,
                                                            h, out, nnz_a);
        }
        int n4 = out_size / 4;
        int blocks = (n4 + 255) / 256; if (blocks > 2048) blocks = 2048;
        relu_kernel<<<blocks, 256, 0, stream>>>(out, n4);
    }
}

// Round 13
// 208.808 us; speedup vs baseline: 1.4922x; 1.0177x over previous
//
#include <hip/hip_runtime.h>
#include <hip/hip_bf16.h>

// GraphSparseConvolution on MI355X.
// Round 13: spmm1 -> 16-deep gather pipeline (L2-hit-latency bound, more MLP);
// bucket_sort -> int4 2-record loads in both streaming passes (start/end are
// PAD-aligned -> 16B-aligned). spmm2 (66us) unchanged: pinned at its
// random-gather bound across 4 rounds. Build pipeline unchanged from r12.
// Fallback to atomic path if ws too small.

static constexpr int O_DIM = 128;
static constexpr float KEEP_INV = 1.0f / 0.9f;  // 1/keep_prob
static constexpr int BUCK_BINS = 256;           // rows per coarse bucket
static constexpr int TILE = 8192;               // edges per multisplit tile
static constexpr int MS_THREADS = 1024;         // threads per build block
static constexpr int MS_ITER = TILE / MS_THREADS;   // 8
static constexpr unsigned PAD_COL = 0x1FFFFu;   // reserved pad marker column

using half_t = _Float16;
using half2_t = _Float16 __attribute__((ext_vector_type(2)));

// ---------------------------------------------------------------------------
// Block 0: detect how the harness materialized the bool keep_mask
// (int32/f32/uint8). Blocks 1..64: convert kernel matrix f32 -> f16.
__global__ void init_kernel(const unsigned int* __restrict__ w, int nwords,
                            int* __restrict__ flags,
                            const float2* __restrict__ kern2,
                            half2_t* __restrict__ k16) {
    int t = threadIdx.x;
    if (blockIdx.x == 0) {
        __shared__ int sA[256];
        __shared__ int sB[256];
        int violA = 0, violB = 0;
        for (int i = t; i < nwords; i += 256) {
            unsigned int x = w[i];
            violA |= (x > 1u) ? 1 : 0;
            violB |= (x != 0u && x != 0x3F800000u) ? 1 : 0;
        }
        sA[t] = violA; sB[t] = violB;
        __syncthreads();
        for (int s = 128; s > 0; s >>= 1) {
            if (t < s) { sA[t] |= sA[t + s]; sB[t] |= sB[t + s]; }
            __syncthreads();
        }
        if (t == 0) { flags[0] = sA[0]; flags[1] = sB[0]; }
    } else {
        int i = (blockIdx.x - 1) * 256 + t;   // 64 blocks x 256 = 16384
        float2 v = kern2[i];
        half2_t o; o.x = (half_t)v.x; o.y = (half_t)v.y;
        k16[i] = o;
    }
}

// ---------------------------------------------------------------------------
// A) per-tile bucket histogram, PADDED to `pad` records per chunk, written
// transposed: histT[k*B + b]. 1024 threads, batched loads.
__global__ __launch_bounds__(MS_THREADS) void tile_hist_kernel(
        const int* __restrict__ xr, int nnz_x,
        const int* __restrict__ ar, int nnz_a,
        int n_nodes, int nbuck, int B, int pad,
        int* __restrict__ histT) {
    __shared__ int hist[1024];
    int b = blockIdx.x, t = threadIdx.x;
    for (int k = t; k < 1024; k += MS_THREADS) hist[k] = 0;
    __syncthreads();
    int tot = nnz_x + nnz_a;
    int tstart = b * TILE;
    int tend = min(tstart + TILE, tot);
    int bin[MS_ITER];
    #pragma unroll
    for (int u = 0; u < MS_ITER; ++u) {
        int i = tstart + t + u * MS_THREADS;
        bin[u] = (i < tend) ? ((i < nnz_x) ? xr[i] : (n_nodes + ar[i - nnz_x])) : -1;
    }
    #pragma unroll
    for (int u = 0; u < MS_ITER; ++u)
        if (bin[u] >= 0) atomicAdd(&hist[bin[u] >> 8], 1);
    __syncthreads();
    int pm = pad - 1;
    for (int k = t; k < nbuck; k += MS_THREADS)
        histT[(size_t)k * B + b] = (hist[k] + pm) & ~pm;
}

// ---------------------------------------------------------------------------
// 3-phase exclusive scan over cnt[0..n) -> S[0..n).
static constexpr int SCAN_BS = 256;
static constexpr int SCAN_IPT = 8;
static constexpr int SCAN_CHUNK = SCAN_BS * SCAN_IPT;  // 2048

__global__ __launch_bounds__(SCAN_BS) void scan_partial_kernel(const int* __restrict__ cnt,
                                                               int n, int* __restrict__ bsums) {
    int b = blockIdx.x, t = threadIdx.x;
    int lane = t & 63, wid = t >> 6;
    __shared__ int wsum[SCAN_BS / 64];
    int base = b * SCAN_CHUNK + t * SCAN_IPT;
    int s = 0;
    #pragma unroll
    for (int k = 0; k < SCAN_IPT; ++k) {
        int i = base + k;
        s += (i < n) ? cnt[i] : 0;
    }
    #pragma unroll
    for (int d = 1; d < 64; d <<= 1) s += __shfl_xor(s, d, 64);
    if (lane == 0) wsum[wid] = s;
    __syncthreads();
    if (t == 0) {
        int tot = 0;
        #pragma unroll
        for (int w = 0; w < SCAN_BS / 64; ++w) tot += wsum[w];
        bsums[b] = tot;
    }
}

__global__ __launch_bounds__(1024) void scan_blocksums_kernel(int* __restrict__ bsums, int nb,
                                                              int* __restrict__ sent0) {
    __shared__ int wsum[16];
    int t = threadIdx.x, lane = t & 63, wid = t >> 6;
    int v = (t < nb) ? bsums[t] : 0;
    int s = v;
    #pragma unroll
    for (int d = 1; d < 64; d <<= 1) {
        int u = __shfl_up(s, d, 64);
        if (lane >= d) s += u;
    }
    if (lane == 63) wsum[wid] = s;
    __syncthreads();
    int woff = 0;
    for (int w = 0; w < wid; ++w) woff += wsum[w];
    if (t < nb) bsums[t] = woff + s - v;      // exclusive
    if (t == 1023) *sent0 = woff + s;         // padded grand total
}

__global__ __launch_bounds__(SCAN_BS) void scan_final_kernel(const int* __restrict__ cnt, int n,
                                                             const int* __restrict__ bsums,
                                                             int* __restrict__ S) {
    __shared__ int wsum[SCAN_BS / 64];
    int b = blockIdx.x, t = threadIdx.x;
    int lane = t & 63, wid = t >> 6;
    int base = b * SCAN_CHUNK + t * SCAN_IPT;
    int v[SCAN_IPT];
    int tsum = 0;
    #pragma unroll
    for (int k = 0; k < SCAN_IPT; ++k) {
        int i = base + k;
        v[k] = (i < n) ? cnt[i] : 0;
        tsum += v[k];
    }
    int s = tsum;
    #pragma unroll
    for (int d = 1; d < 64; d <<= 1) {
        int u = __shfl_up(s, d, 64);
        if (lane >= d) s += u;
    }
    if (lane == 63) wsum[wid] = s;
    __syncthreads();
    int woff = 0;
    for (int w = 0; w < wid; ++w) woff += wsum[w];
    int excl = bsums[b] + woff + (s - tsum);
    #pragma unroll
    for (int k = 0; k < SCAN_IPT; ++k) {
        int i = base + k;
        if (i < n) S[i] = excl;
        excl += v[k];
    }
}

// ---------------------------------------------------------------------------
// C) multisplit: deterministic placement via LDS cursors seeded from tofs.
// 1024 threads; all MS_ITER iterations' inputs preloaded into registers,
// then the atomic+store chain runs. Pad-fill with marked records at the end
// (line-exclusive writes; pads dropped by bucket_sort).
__global__ __launch_bounds__(MS_THREADS) void multisplit_kernel(
        const float* __restrict__ xv,
        const int* __restrict__ xr,
        const int* __restrict__ xc,
        const void* __restrict__ mask,
        const int* __restrict__ flags,
        const float* __restrict__ av,
        const int* __restrict__ ar,
        const int* __restrict__ ac,
        int nnz_x, int nnz_a, int n_nodes,
        int nbuck, int B,
        const int* __restrict__ tofs,
        int2* __restrict__ rec) {
    __shared__ int cur[1024];
    int b = blockIdx.x, t = threadIdx.x;
    for (int k = t; k < nbuck; k += MS_THREADS)
        cur[k] = tofs[(size_t)k * B + b];
    __syncthreads();
    int tot = nnz_x + nnz_a;
    int tstart = b * TILE;
    int tend = min(tstart + TILE, tot);
    int f0 = flags[0], f1 = flags[1];

    int bin[MS_ITER], col[MS_ITER];
    float val[MS_ITER];
    #pragma unroll
    for (int u = 0; u < MS_ITER; ++u) {
        int i = tstart + t + u * MS_THREADS;
        bin[u] = -1;
        if (i < tend) {
            if (i < nnz_x) {
                bin[u] = xr[i];
                col[u] = xc[i];
                bool keep;
                if (f0 == 0)      keep = ((const int*)mask)[i] != 0;
                else if (f1 == 0) keep = ((const float*)mask)[i] != 0.0f;
                else              keep = ((const unsigned char*)mask)[i] != 0;
                val[u] = keep ? xv[i] * KEEP_INV : 0.0f;
            } else {
                int e = i - nnz_x;
                bin[u] = n_nodes + ar[e];
                col[u] = ac[e];
                val[u] = av[e];
            }
        }
    }
    #pragma unroll
    for (int u = 0; u < MS_ITER; ++u) {
        if (bin[u] >= 0) {
            int key = ((bin[u] & (BUCK_BINS - 1)) << 17) | col[u];
            int pos = atomicAdd(&cur[bin[u] >> 8], 1);   // LDS atomic — cheap
            rec[pos] = make_int2(key, __float_as_int(val[u]));
        }
    }
    __syncthreads();
    // pad-fill with marked records (col = PAD_COL -> dropped in bucket_sort)
    int fillkey = (int)((((unsigned)b & (BUCK_BINS - 1)) << 17) | PAD_COL);
    for (int k = t; k < nbuck; k += MS_THREADS) {
        int fl = k * B + b;
        int pe = tofs[fl + 1];
        for (int p = cur[k]; p < pe; ++p)
            rec[p] = make_int2(fillkey, 0);
    }
}

// ---------------------------------------------------------------------------
// D) per-bucket LDS counting sort over REAL records -> packed + exact
// per-row [S, E) bounds. 512 threads; int4 2-record loads (start/end are
// PAD-aligned -> 16B-aligned).
__global__ __launch_bounds__(512) void bucket_sort_kernel(
        const int2* __restrict__ rec,
        const int* __restrict__ tofs, int B,
        int ntot, int2* __restrict__ packed,
        int* __restrict__ S, int* __restrict__ E) {
    __shared__ int hist[256];
    __shared__ int cur[256];
    __shared__ int wsum[4];
    int bb = blockIdx.x, t = threadIdx.x;
    int start = tofs[(size_t)bb * B];
    int end   = tofs[(size_t)(bb + 1) * B];
    if (t < 256) hist[t] = 0;
    __syncthreads();
    // pass 1: histogram real records (2 records per int4 load)
    for (int i = start + t * 2; i < end; i += 1024) {
        int4 p = *(const int4*)(rec + i);
        unsigned k0 = (unsigned)p.x, k1 = (unsigned)p.z;
        if ((k0 & PAD_COL) != PAD_COL) atomicAdd(&hist[k0 >> 17], 1);
        if (i + 1 < end && (k1 & PAD_COL) != PAD_COL) atomicAdd(&hist[k1 >> 17], 1);
    }
    __syncthreads();
    int v = 0, s = 0;
    int lane = t & 63, wid = t >> 6;
    if (t < 256) {                       // waves 0..3 scan the 256 bins
        v = hist[t];
        s = v;
        #pragma unroll
        for (int d = 1; d < 64; d <<= 1) {
            int u = __shfl_up(s, d, 64);
            if (lane >= d) s += u;
        }
        if (lane == 63) wsum[wid] = s;
    }
    __syncthreads();
    if (t < 256) {
        int woff = 0;
        for (int w = 0; w < wid; ++w) woff += wsum[w];
        int excl = woff + s - v;
        int binBase = bb << 8;
        if (binBase + t < ntot) {
            S[binBase + t] = start + excl;
            E[binBase + t] = start + excl + v;
        }
        cur[t] = start + excl;
    }
    __syncthreads();
    // pass 2: rank & scatter real records (2 per int4 load)
    for (int i = start + t * 2; i < end; i += 1024) {
        int4 p = *(const int4*)(rec + i);
        unsigned k0 = (unsigned)p.x, k1 = (unsigned)p.z;
        if ((k0 & PAD_COL) != PAD_COL) {
            int pos = atomicAdd(&cur[k0 >> 17], 1);
            packed[pos] = make_int2((int)(k0 & PAD_COL), p.y);
        }
        if (i + 1 < end && (k1 & PAD_COL) != PAD_COL) {
            int pos = atomicAdd(&cur[k1 >> 17], 1);
            packed[pos] = make_int2((int)(k1 & PAD_COL), p.w);
        }
    }
}

// ---------------------------------------------------------------------------
// E) SpMM1: wave-per-row, f16 weight gathers from the 64KB L2-hot table,
// int4 edge loads, 16-deep gather pipeline with 8/4/scalar tails.
__global__ __launch_bounds__(256) void spmm1_wave_kernel(
        const int* __restrict__ S, const int* __restrict__ E,
        const int2* __restrict__ packed,
        const half2_t* __restrict__ k16, half2_t* __restrict__ h2,
        int n_rows) {
    int gid = blockIdx.x * 256 + threadIdx.x;
    int r = gid >> 6;
    if (r >= n_rows) return;
    int lane = gid & 63;
    int j = S[r], end = E[r];
    float ax = 0.0f, ay = 0.0f;
    if ((j & 1) && j < end) {   // peel to 16B-align packed reads
        int2 e = packed[j];
        half2_t w = k16[e.x * 64 + lane];
        float v = __int_as_float(e.y);
        ax = fmaf(v, (float)w.x, ax); ay = fmaf(v, (float)w.y, ay);
        ++j;
    }
    for (; j + 16 <= end; j += 16) {
        int4 p0 = *(const int4*)(packed + j);
        int4 p1 = *(const int4*)(packed + j + 2);
        int4 p2 = *(const int4*)(packed + j + 4);
        int4 p3 = *(const int4*)(packed + j + 6);
        int4 p4 = *(const int4*)(packed + j + 8);
        int4 p5 = *(const int4*)(packed + j + 10);
        int4 p6 = *(const int4*)(packed + j + 12);
        int4 p7 = *(const int4*)(packed + j + 14);
        half2_t w0 = k16[p0.x * 64 + lane];
        half2_t w1 = k16[p0.z * 64 + lane];
        half2_t w2 = k16[p1.x * 64 + lane];
        half2_t w3 = k16[p1.z * 64 + lane];
        half2_t w4 = k16[p2.x * 64 + lane];
        half2_t w5 = k16[p2.z * 64 + lane];
        half2_t w6 = k16[p3.x * 64 + lane];
        half2_t w7 = k16[p3.z * 64 + lane];
        half2_t w8 = k16[p4.x * 64 + lane];
        half2_t w9 = k16[p4.z * 64 + lane];
        half2_t wa = k16[p5.x * 64 + lane];
        half2_t wb = k16[p5.z * 64 + lane];
        half2_t wc = k16[p6.x * 64 + lane];
        half2_t wd = k16[p6.z * 64 + lane];
        half2_t we = k16[p7.x * 64 + lane];
        half2_t wf = k16[p7.z * 64 + lane];
        float v0 = __int_as_float(p0.y), v1 = __int_as_float(p0.w);
        float v2 = __int_as_float(p1.y), v3 = __int_as_float(p1.w);
        float v4 = __int_as_float(p2.y), v5 = __int_as_float(p2.w);
        float v6 = __int_as_float(p3.y), v7 = __int_as_float(p3.w);
        float v8 = __int_as_float(p4.y), v9 = __int_as_float(p4.w);
        float va = __int_as_float(p5.y), vb = __int_as_float(p5.w);
        float vc = __int_as_float(p6.y), vd = __int_as_float(p6.w);
        float ve = __int_as_float(p7.y), vf = __int_as_float(p7.w);
        ax = fmaf(v0, (float)w0.x, ax); ay = fmaf(v0, (float)w0.y, ay);
        ax = fmaf(v1, (float)w1.x, ax); ay = fmaf(v1, (float)w1.y, ay);
        ax = fmaf(v2, (float)w2.x, ax); ay = fmaf(v2, (float)w2.y, ay);
        ax = fmaf(v3, (float)w3.x, ax); ay = fmaf(v3, (float)w3.y, ay);
        ax = fmaf(v4, (float)w4.x, ax); ay = fmaf(v4, (float)w4.y, ay);
        ax = fmaf(v5, (float)w5.x, ax); ay = fmaf(v5, (float)w5.y, ay);
        ax = fmaf(v6, (float)w6.x, ax); ay = fmaf(v6, (float)w6.y, ay);
        ax = fmaf(v7, (float)w7.x, ax); ay = fmaf(v7, (float)w7.y, ay);
        ax = fmaf(v8, (float)w8.x, ax); ay = fmaf(v8, (float)w8.y, ay);
        ax = fmaf(v9, (float)w9.x, ax); ay = fmaf(v9, (float)w9.y, ay);
        ax = fmaf(va, (float)wa.x, ax); ay = fmaf(va, (float)wa.y, ay);
        ax = fmaf(vb, (float)wb.x, ax); ay = fmaf(vb, (float)wb.y, ay);
        ax = fmaf(vc, (float)wc.x, ax); ay = fmaf(vc, (float)wc.y, ay);
        ax = fmaf(vd, (float)wd.x, ax); ay = fmaf(vd, (float)wd.y, ay);
        ax = fmaf(ve, (float)we.x, ax); ay = fmaf(ve, (float)we.y, ay);
        ax = fmaf(vf, (float)wf.x, ax); ay = fmaf(vf, (float)wf.y, ay);
    }
    if (j + 8 <= end) {
        int4 p0 = *(const int4*)(packed + j);
        int4 p1 = *(const int4*)(packed + j + 2);
        int4 p2 = *(const int4*)(packed + j + 4);
        int4 p3 = *(const int4*)(packed + j + 6);
        half2_t w0 = k16[p0.x * 64 + lane];
        half2_t w1 = k16[p0.z * 64 + lane];
        half2_t w2 = k16[p1.x * 64 + lane];
        half2_t w3 = k16[p1.z * 64 + lane];
        half2_t w4 = k16[p2.x * 64 + lane];
        half2_t w5 = k16[p2.z * 64 + lane];
        half2_t w6 = k16[p3.x * 64 + lane];
        half2_t w7 = k16[p3.z * 64 + lane];
        float v0 = __int_as_float(p0.y), v1 = __int_as_float(p0.w);
        float v2 = __int_as_float(p1.y), v3 = __int_as_float(p1.w);
        float v4 = __int_as_float(p2.y), v5 = __int_as_float(p2.w);
        float v6 = __int_as_float(p3.y), v7 = __int_as_float(p3.w);
        ax = fmaf(v0, (float)w0.x, ax); ay = fmaf(v0, (float)w0.y, ay);
        ax = fmaf(v1, (float)w1.x, ax); ay = fmaf(v1, (float)w1.y, ay);
        ax = fmaf(v2, (float)w2.x, ax); ay = fmaf(v2, (float)w2.y, ay);
        ax = fmaf(v3, (float)w3.x, ax); ay = fmaf(v3, (float)w3.y, ay);
        ax = fmaf(v4, (float)w4.x, ax); ay = fmaf(v4, (float)w4.y, ay);
        ax = fmaf(v5, (float)w5.x, ax); ay = fmaf(v5, (float)w5.y, ay);
        ax = fmaf(v6, (float)w6.x, ax); ay = fmaf(v6, (float)w6.y, ay);
        ax = fmaf(v7, (float)w7.x, ax); ay = fmaf(v7, (float)w7.y, ay);
        j += 8;
    }
    if (j + 4 <= end) {
        int4 p0 = *(const int4*)(packed + j);
        int4 p1 = *(const int4*)(packed + j + 2);
        half2_t w0 = k16[p0.x * 64 + lane];
        half2_t w1 = k16[p0.z * 64 + lane];
        half2_t w2 = k16[p1.x * 64 + lane];
        half2_t w3 = k16[p1.z * 64 + lane];
        float v0 = __int_as_float(p0.y), v1 = __int_as_float(p0.w);
        float v2 = __int_as_float(p1.y), v3 = __int_as_float(p1.w);
        ax = fmaf(v0, (float)w0.x, ax); ay = fmaf(v0, (float)w0.y, ay);
        ax = fmaf(v1, (float)w1.x, ax); ay = fmaf(v1, (float)w1.y, ay);
        ax = fmaf(v2, (float)w2.x, ax); ay = fmaf(v2, (float)w2.y, ay);
        ax = fmaf(v3, (float)w3.x, ax); ay = fmaf(v3, (float)w3.y, ay);
        j += 4;
    }
    for (; j < end; ++j) {
        int2 e = packed[j];
        half2_t w = k16[e.x * 64 + lane];
        float v = __int_as_float(e.y);
        ax = fmaf(v, (float)w.x, ax); ay = fmaf(v, (float)w.y, ay);
    }
    half2_t o; o.x = (half_t)ax; o.y = (half_t)ay;
    h2[r * 64 + lane] = o;
}

// ---------------------------------------------------------------------------
// F) SpMM2 + ReLU: wave-per-row, 16-deep gather pipeline with 8/4/scalar
// tails, int4 edge loads. At the random-gather roofline (~6.2 TB/s logical).
__global__ __launch_bounds__(256) void spmm2_wave_kernel(
        const int* __restrict__ S, const int* __restrict__ E,
        const int2* __restrict__ packed,
        const half2_t* __restrict__ h2, float2* __restrict__ out2,
        int n_rows) {
    int gid = blockIdx.x * 256 + threadIdx.x;
    int r = gid >> 6;
    if (r >= n_rows) return;
    int lane = gid & 63;
    int j = S[r], end = E[r];
    float ax = 0.0f, ay = 0.0f;
    if ((j & 1) && j < end) {
        int2 e = packed[j];
        half2_t w = h2[e.x * 64 + lane];
        float v = __int_as_float(e.y);
        ax = fmaf(v, (float)w.x, ax); ay = fmaf(v, (float)w.y, ay);
        ++j;
    }
    for (; j + 16 <= end; j += 16) {
        int4 p0 = *(const int4*)(packed + j);
        int4 p1 = *(const int4*)(packed + j + 2);
        int4 p2 = *(const int4*)(packed + j + 4);
        int4 p3 = *(const int4*)(packed + j + 6);
        int4 p4 = *(const int4*)(packed + j + 8);
        int4 p5 = *(const int4*)(packed + j + 10);
        int4 p6 = *(const int4*)(packed + j + 12);
        int4 p7 = *(const int4*)(packed + j + 14);
        half2_t w0 = h2[p0.x * 64 + lane];
        half2_t w1 = h2[p0.z * 64 + lane];
        half2_t w2 = h2[p1.x * 64 + lane];
        half2_t w3 = h2[p1.z * 64 + lane];
        half2_t w4 = h2[p2.x * 64 + lane];
        half2_t w5 = h2[p2.z * 64 + lane];
        half2_t w6 = h2[p3.x * 64 + lane];
        half2_t w7 = h2[p3.z * 64 + lane];
        half2_t w8 = h2[p4.x * 64 + lane];
        half2_t w9 = h2[p4.z * 64 + lane];
        half2_t wa = h2[p5.x * 64 + lane];
        half2_t wb = h2[p5.z * 64 + lane];
        half2_t wc = h2[p6.x * 64 + lane];
        half2_t wd = h2[p6.z * 64 + lane];
        half2_t we = h2[p7.x * 64 + lane];
        half2_t wf = h2[p7.z * 64 + lane];
        float v0 = __int_as_float(p0.y), v1 = __int_as_float(p0.w);
        float v2 = __int_as_float(p1.y), v3 = __int_as_float(p1.w);
        float v4 = __int_as_float(p2.y), v5 = __int_as_float(p2.w);
        float v6 = __int_as_float(p3.y), v7 = __int_as_float(p3.w);
        float v8 = __int_as_float(p4.y), v9 = __int_as_float(p4.w);
        float va = __int_as_float(p5.y), vb = __int_as_float(p5.w);
        float vc = __int_as_float(p6.y), vd = __int_as_float(p6.w);
        float ve = __int_as_float(p7.y), vf = __int_as_float(p7.w);
        ax = fmaf(v0, (float)w0.x, ax); ay = fmaf(v0, (float)w0.y, ay);
        ax = fmaf(v1, (float)w1.x, ax); ay = fmaf(v1, (float)w1.y, ay);
        ax = fmaf(v2, (float)w2.x, ax); ay = fmaf(v2, (float)w2.y, ay);
        ax = fmaf(v3, (float)w3.x, ax); ay = fmaf(v3, (float)w3.y, ay);
        ax = fmaf(v4, (float)w4.x, ax); ay = fmaf(v4, (float)w4.y, ay);
        ax = fmaf(v5, (float)w5.x, ax); ay = fmaf(v5, (float)w5.y, ay);
        ax = fmaf(v6, (float)w6.x, ax); ay = fmaf(v6, (float)w6.y, ay);
        ax = fmaf(v7, (float)w7.x, ax); ay = fmaf(v7, (float)w7.y, ay);
        ax = fmaf(v8, (float)w8.x, ax); ay = fmaf(v8, (float)w8.y, ay);
        ax = fmaf(v9, (float)w9.x, ax); ay = fmaf(v9, (float)w9.y, ay);
        ax = fmaf(va, (float)wa.x, ax); ay = fmaf(va, (float)wa.y, ay);
        ax = fmaf(vb, (float)wb.x, ax); ay = fmaf(vb, (float)wb.y, ay);
        ax = fmaf(vc, (float)wc.x, ax); ay = fmaf(vc, (float)wc.y, ay);
        ax = fmaf(vd, (float)wd.x, ax); ay = fmaf(vd, (float)wd.y, ay);
        ax = fmaf(ve, (float)we.x, ax); ay = fmaf(ve, (float)we.y, ay);
        ax = fmaf(vf, (float)wf.x, ax); ay = fmaf(vf, (float)wf.y, ay);
    }
    if (j + 8 <= end) {
        int4 p0 = *(const int4*)(packed + j);
        int4 p1 = *(const int4*)(packed + j + 2);
        int4 p2 = *(const int4*)(packed + j + 4);
        int4 p3 = *(const int4*)(packed + j + 6);
        half2_t w0 = h2[p0.x * 64 + lane];
        half2_t w1 = h2[p0.z * 64 + lane];
        half2_t w2 = h2[p1.x * 64 + lane];
        half2_t w3 = h2[p1.z * 64 + lane];
        half2_t w4 = h2[p2.x * 64 + lane];
        half2_t w5 = h2[p2.z * 64 + lane];
        half2_t w6 = h2[p3.x * 64 + lane];
        half2_t w7 = h2[p3.z * 64 + lane];
        float v0 = __int_as_float(p0.y), v1 = __int_as_float(p0.w);
        float v2 = __int_as_float(p1.y), v3 = __int_as_float(p1.w);
        float v4 = __int_as_float(p2.y), v5 = __int_as_float(p2.w);
        float v6 = __int_as_float(p3.y), v7 = __int_as_float(p3.w);
        ax = fmaf(v0, (float)w0.x, ax); ay = fmaf(v0, (float)w0.y, ay);
        ax = fmaf(v1, (float)w1.x, ax); ay = fmaf(v1, (float)w1.y, ay);
        ax = fmaf(v2, (float)w2.x, ax); ay = fmaf(v2, (float)w2.y, ay);
        ax = fmaf(v3, (float)w3.x, ax); ay = fmaf(v3, (float)w3.y, ay);
        ax = fmaf(v4, (float)w4.x, ax); ay = fmaf(v4, (float)w4.y, ay);
        ax = fmaf(v5, (float)w5.x, ax); ay = fmaf(v5, (float)w5.y, ay);
        ax = fmaf(v6, (float)w6.x, ax); ay = fmaf(v6, (float)w6.y, ay);
        ax = fmaf(v7, (float)w7.x, ax); ay = fmaf(v7, (float)w7.y, ay);
        j += 8;
    }
    if (j + 4 <= end) {
        int4 p0 = *(const int4*)(packed + j);
        int4 p1 = *(const int4*)(packed + j + 2);
        half2_t w0 = h2[p0.x * 64 + lane];
        half2_t w1 = h2[p0.z * 64 + lane];
        half2_t w2 = h2[p1.x * 64 + lane];
        half2_t w3 = h2[p1.z * 64 + lane];
        float v0 = __int_as_float(p0.y), v1 = __int_as_float(p0.w);
        float v2 = __int_as_float(p1.y), v3 = __int_as_float(p1.w);
        ax = fmaf(v0, (float)w0.x, ax); ay = fmaf(v0, (float)w0.y, ay);
        ax = fmaf(v1, (float)w1.x, ax); ay = fmaf(v1, (float)w1.y, ay);
        ax = fmaf(v2, (float)w2.x, ax); ay = fmaf(v2, (float)w2.y, ay);
        ax = fmaf(v3, (float)w3.x, ax); ay = fmaf(v3, (float)w3.y, ay);
        j += 4;
    }
    for (; j < end; ++j) {
        int2 e = packed[j];
        half2_t w = h2[e.x * 64 + lane];
        float v = __int_as_float(e.y);
        ax = fmaf(v, (float)w.x, ax); ay = fmaf(v, (float)w.y, ay);
    }
    out2[r * 64 + lane] = make_float2(fmaxf(ax, 0.0f), fmaxf(ay, 0.0f));
}

// ---------------------------------------------------------------------------
// Fallback atomic path (only if ws too small).
__global__ void fb_detect_mask_kernel(const unsigned int* __restrict__ w, int nwords,
                                      int* __restrict__ flags) {
    __shared__ int sA[256];
    __shared__ int sB[256];
    int t = threadIdx.x;
    int violA = 0, violB = 0;
    for (int i = t; i < nwords; i += 256) {
        unsigned int x = w[i];
        violA |= (x > 1u) ? 1 : 0;
        violB |= (x != 0u && x != 0x3F800000u) ? 1 : 0;
    }
    sA[t] = violA; sB[t] = violB;
    __syncthreads();
    for (int s = 128; s > 0; s >>= 1) {
        if (t < s) { sA[t] |= sA[t + s]; sB[t] |= sB[t + s]; }
        __syncthreads();
    }
    if (t == 0) { flags[0] = sA[0]; flags[1] = sB[0]; }
}

__global__ void spmm1_atomic_kernel(const float* __restrict__ xv,
                                    const int* __restrict__ xr,
                                    const int* __restrict__ xc,
                                    const void* __restrict__ mask,
                                    const float* __restrict__ kern,
                                    const int* __restrict__ flags,
                                    float* __restrict__ h, int nnz) {
    long long gid = (long long)blockIdx.x * blockDim.x + threadIdx.x;
    int e = (int)(gid >> 7);
    if (e >= nnz) return;
    int o = (int)(gid & 127);
    bool keep;
    if (flags[0] == 0)      keep = ((const int*)mask)[e] != 0;
    else if (flags[1] == 0) keep = ((const float*)mask)[e] != 0.0f;
    else                    keep = ((const unsigned char*)mask)[e] != 0;
    if (!keep) return;
    atomicAdd(&h[(long long)xr[e] * O_DIM + o], xv[e] * KEEP_INV * kern[xc[e] * O_DIM + o]);
}

__global__ void spmm2_atomic_kernel(const float* __restrict__ av,
                                    const int* __restrict__ ar,
                                    const int* __restrict__ ac,
                                    const float* __restrict__ h,
                                    float* __restrict__ out, int nnz) {
    long long gid = (long long)blockIdx.x * blockDim.x + threadIdx.x;
    int e = (int)(gid >> 7);
    if (e >= nnz) return;
    int o = (int)(gid & 127);
    atomicAdd(&out[(long long)ar[e] * O_DIM + o], av[e] * h[(long long)ac[e] * O_DIM + o]);
}

__global__ void relu_kernel(float* __restrict__ out, int n4) {
    int stride = gridDim.x * blockDim.x;
    float4* p = (float4*)out;
    for (int i = blockIdx.x * blockDim.x + threadIdx.x; i < n4; i += stride) {
        float4 v = p[i];
        v.x = fmaxf(v.x, 0.0f); v.y = fmaxf(v.y, 0.0f);
        v.z = fmaxf(v.z, 0.0f); v.w = fmaxf(v.w, 0.0f);
        p[i] = v;
    }
}

// ---------------------------------------------------------------------------
static inline size_t align256(size_t x) { return (x + 255) & ~(size_t)255; }

extern "C" void kernel_launch(void* const* d_in, const int* in_sizes, int n_in,
                              void* d_out, int out_size, void* d_ws, size_t ws_size,
                              hipStream_t stream) {
    const float* x_vals   = (const float*)d_in[0];
    const float* kern     = (const float*)d_in[1];   // [256 x 128]
    const float* adj_vals = (const float*)d_in[2];
    const int*   x_rows   = (const int*)d_in[3];
    const int*   x_cols   = (const int*)d_in[4];
    const int*   adj_rows = (const int*)d_in[5];
    const int*   adj_cols = (const int*)d_in[6];
    const void*  mask     = d_in[7];

    const int nnz_x = in_sizes[0];
    const int nnz_a = in_sizes[2];
    const int n_nodes = out_size / O_DIM;
    const int ntot = 2 * n_nodes;
    const int nbuck = (ntot + BUCK_BINS - 1) / BUCK_BINS;
    const long long nnz_tot = (long long)nnz_x + nnz_a;
    const int B = (int)((nnz_tot + TILE - 1) / TILE);           // tiles
    const long long n_scan = (long long)nbuck * B;              // KxB matrix
    const int nb_scan = (int)((n_scan + SCAN_CHUNK - 1) / SCAN_CHUNK);

    float* out = (float*)d_out;
    char* ws = (char*)d_ws;

    // ---- ws carve-up: fixed buffers first, then PAD-dependent rec/packed ----
    size_t off = 0;
    int* flags = (int*)d_ws;            off = align256(off + 2 * sizeof(int));
    size_t o_k16 = off;                 off = align256(off + 256 * 128 * sizeof(half_t));
    size_t o_histT = off;               off = align256(off + (size_t)n_scan * 4);
    size_t o_tofs = off;                off = align256(off + ((size_t)n_scan + 1) * 4);
    size_t o_bsums = off;               off = align256(off + 4096 * 4);
    size_t o_S = off;                   off = align256(off + ((size_t)ntot + 1) * 4);
    size_t o_E = off;                   off = align256(off + (size_t)ntot * 4);
    size_t o_h = off;                   off = align256(off + (size_t)n_nodes * O_DIM * sizeof(half_t));
    const size_t fixed_end = off;

    // choose largest PAD in {8,4,2} whose worst-case rec+packed fit ws
    // (PAD>=2 keeps chunk starts 16B-aligned for bucket_sort's int4 loads)
    int PAD = 8;
    long long rec_cap = 0;
    while (true) {
        rec_cap = nnz_tot + (long long)(PAD - 1) * n_scan;   // worst-case records
        size_t need = fixed_end + 2 * align256((size_t)rec_cap * 8);
        if (need <= ws_size || PAD == 2) break;
        PAD >>= 1;
    }
    size_t o_rec = fixed_end;
    size_t o_packed = o_rec + align256((size_t)rec_cap * 8);
    size_t total_need = o_packed + align256((size_t)rec_cap * 8);

    const bool csr_ok = (total_need <= ws_size) && (nbuck <= 1024) &&
                        (n_nodes < (1 << 17)) && (nb_scan <= 1024);

    int scan_words = nnz_x / 4;
    if (scan_words > 16384) scan_words = 16384;

    if (csr_ok) {
        half2_t* k16 = (half2_t*)(ws + o_k16);
        int*  histT  = (int*)(ws + o_histT);
        int*  tofs   = (int*)(ws + o_tofs);
        int*  bsums  = (int*)(ws + o_bsums);
        int*  S      = (int*)(ws + o_S);
        int*  E      = (int*)(ws + o_E);
        int2* rec    = (int2*)(ws + o_rec);
        int2* packed = (int2*)(ws + o_packed);
        half2_t* h2  = (half2_t*)(ws + o_h);

        // 0) mask detect + kernel f32->f16 (fused: block 0 / blocks 1..64)
        init_kernel<<<65, 256, 0, stream>>>((const unsigned int*)mask, scan_words,
                                            flags, (const float2*)kern, k16);
        // A) per-tile bucket histograms (transposed, padded to PAD records)
        tile_hist_kernel<<<B, MS_THREADS, 0, stream>>>(x_rows, nnz_x, adj_rows, nnz_a,
                                                       n_nodes, nbuck, B, PAD, histT);
        // B) exclusive scan of the KxB matrix -> line-aligned chunk offsets
        scan_partial_kernel<<<nb_scan, SCAN_BS, 0, stream>>>(histT, (int)n_scan, bsums);
        scan_blocksums_kernel<<<1, 1024, 0, stream>>>(bsums, nb_scan, &tofs[n_scan]);
        scan_final_kernel<<<nb_scan, SCAN_BS, 0, stream>>>(histT, (int)n_scan, bsums, tofs);
        // C) multisplit: deterministic scatter + marked pad fill
        multisplit_kernel<<<B, MS_THREADS, 0, stream>>>(x_vals, x_rows, x_cols, mask, flags,
                                                        adj_vals, adj_rows, adj_cols,
                                                        nnz_x, nnz_a, n_nodes, nbuck, B,
                                                        tofs, rec);
        // D) per-bucket counting sort (drops pads) -> packed + exact [S,E)
        bucket_sort_kernel<<<nbuck, 512, 0, stream>>>(rec, tofs, B, ntot, packed, S, E);
        // E) SpMM1 (f16 weight gathers): h = dropout(X) @ kernel
        {
            int blocks = (n_nodes * 64 + 255) / 256;
            spmm1_wave_kernel<<<blocks, 256, 0, stream>>>(S, E, packed, k16, h2, n_nodes);
        }
        // F) SpMM2 + ReLU: out = relu(adj @ h)
        {
            int blocks = (n_nodes * 64 + 255) / 256;
            spmm2_wave_kernel<<<blocks, 256, 0, stream>>>(S + n_nodes, E + n_nodes,
                                                          packed, h2, (float2*)out, n_nodes);
        }
    } else {
        // ---- fallback: atomic path ----
        fb_detect_mask_kernel<<<1, 256, 0, stream>>>((const unsigned int*)mask,
                                                     scan_words, flags);
        float* h = (float*)(ws + 256);
        hipMemsetAsync(h, 0, (size_t)n_nodes * O_DIM * 4, stream);
        hipMemsetAsync(out, 0, (size_t)out_size * 4, stream);
        {
            long long threads = (long long)nnz_x * O_DIM;
            int blocks = (int)((threads + 255) / 256);
            spmm1_atomic_kernel<<<blocks, 256, 0, stream>>>(x_vals, x_rows, x_cols, mask,
                                                            kern, flags, h, nnz_x);
            threads = (long long)nnz_a * O_DIM;
            blocks = (int)((threads + 255) / 256);
            spmm2_atomic_kernel<<<blocks, 256, 0, stream>>>(adj_vals, adj_rows, adj_cols,
                                                            h, out, nnz_a);
        }
        int n4 = out_size / 4;
        int blocks = (n4 + 255) / 256; if (blocks > 2048) blocks = 2048;
        relu_kernel<<<blocks, 256, 0, stream>>>(out, n4);
    }
}